// Round 2
// baseline (12666.840 us; speedup 1.0000x reference)
//
#include <hip/hip_runtime.h>
#include <hip/hip_bf16.h>
#include <math.h>

// ---------------------------------------------------------------------------
// MoleculeGNS fused fp32 baseline, workspace-size-adaptive e-storage.
// LDS tiles transposed xs[k][t], t-stride STRIDE=20 floats (80B, 16B-aligned).
// Each block: TILE=16 rows, 256 threads.
// ---------------------------------------------------------------------------

#define TILE   16
#define STRIDE 20

__device__ __forceinline__ float silu_f(float x) {
  return x / (1.0f + expf(-x));
}

// e-storage element access (fp32 or bf16), arithmetic always fp32.
__device__ __forceinline__ float loadE(const float* p)          { return *p; }
__device__ __forceinline__ float loadE(const __hip_bfloat16* p) { return __bfloat162float(*p); }
__device__ __forceinline__ void  storeE(float* p, float v)          { *p = v; }
__device__ __forceinline__ void  storeE(__hip_bfloat16* p, float v) { *p = __float2bfloat16(v); }

// Layer 1: [TILE,K1] @ [K1,256] + b1, silu -> hs (transposed, stride 20).
template<int K1>
__device__ __forceinline__ void layer1_silu(const float* __restrict__ xs,
                                            const float* __restrict__ w1,
                                            const float* __restrict__ b1,
                                            float* __restrict__ hs, int tid)
{
  const int jh = tid & 127;
  const int tp = tid >> 7;
  const int tbase = 8 * tp;
  float a[8] = {0,0,0,0,0,0,0,0};
  float b[8] = {0,0,0,0,0,0,0,0};
  const float* wp = w1 + jh;
  for (int k = 0; k < K1; ++k) {
    const float4 x0 = *(const float4*)&xs[k*STRIDE + tbase];
    const float4 x1 = *(const float4*)&xs[k*STRIDE + tbase + 4];
    const float wa = wp[k*256];
    const float wb = wp[k*256 + 128];
    a[0] = fmaf(x0.x, wa, a[0]); a[1] = fmaf(x0.y, wa, a[1]);
    a[2] = fmaf(x0.z, wa, a[2]); a[3] = fmaf(x0.w, wa, a[3]);
    a[4] = fmaf(x1.x, wa, a[4]); a[5] = fmaf(x1.y, wa, a[5]);
    a[6] = fmaf(x1.z, wa, a[6]); a[7] = fmaf(x1.w, wa, a[7]);
    b[0] = fmaf(x0.x, wb, b[0]); b[1] = fmaf(x0.y, wb, b[1]);
    b[2] = fmaf(x0.z, wb, b[2]); b[3] = fmaf(x0.w, wb, b[3]);
    b[4] = fmaf(x1.x, wb, b[4]); b[5] = fmaf(x1.y, wb, b[5]);
    b[6] = fmaf(x1.z, wb, b[6]); b[7] = fmaf(x1.w, wb, b[7]);
  }
  const float ba = b1[jh];
  const float bb = b1[jh + 128];
  float4 oa0, oa1, ob0, ob1;
  oa0.x = silu_f(a[0] + ba); oa0.y = silu_f(a[1] + ba);
  oa0.z = silu_f(a[2] + ba); oa0.w = silu_f(a[3] + ba);
  oa1.x = silu_f(a[4] + ba); oa1.y = silu_f(a[5] + ba);
  oa1.z = silu_f(a[6] + ba); oa1.w = silu_f(a[7] + ba);
  ob0.x = silu_f(b[0] + bb); ob0.y = silu_f(b[1] + bb);
  ob0.z = silu_f(b[2] + bb); ob0.w = silu_f(b[3] + bb);
  ob1.x = silu_f(b[4] + bb); ob1.y = silu_f(b[5] + bb);
  ob1.z = silu_f(b[6] + bb); ob1.w = silu_f(b[7] + bb);
  *(float4*)&hs[jh*STRIDE + tbase]           = oa0;
  *(float4*)&hs[jh*STRIDE + tbase + 4]       = oa1;
  *(float4*)&hs[(jh+128)*STRIDE + tbase]     = ob0;
  *(float4*)&hs[(jh+128)*STRIDE + tbase + 4] = ob1;
}

// Layer 2: [TILE,256] @ [256,128] + b2 (no activation).
__device__ __forceinline__ void layer2_bias(const float* __restrict__ hs,
                                            const float* __restrict__ w2,
                                            const float* __restrict__ b2,
                                            int tid, float cA[4], float cB[4])
{
  const int dh = tid & 63;
  const int tq = tid >> 6;
  const int tbase = 4 * tq;
  cA[0]=cA[1]=cA[2]=cA[3]=0.0f;
  cB[0]=cB[1]=cB[2]=cB[3]=0.0f;
  const float* wp = w2 + dh;
  for (int k = 0; k < 256; ++k) {
    const float4 hv = *(const float4*)&hs[k*STRIDE + tbase];
    const float wa = wp[k*128];
    const float wb = wp[k*128 + 64];
    cA[0] = fmaf(hv.x, wa, cA[0]); cA[1] = fmaf(hv.y, wa, cA[1]);
    cA[2] = fmaf(hv.z, wa, cA[2]); cA[3] = fmaf(hv.w, wa, cA[3]);
    cB[0] = fmaf(hv.x, wb, cB[0]); cB[1] = fmaf(hv.y, wb, cB[1]);
    cB[2] = fmaf(hv.z, wb, cB[2]); cB[3] = fmaf(hv.w, wb, cB[3]);
  }
  const float b2a = b2[dh];
  const float b2b = b2[dh + 64];
  #pragma unroll
  for (int tt = 0; tt < 4; ++tt) { cA[tt] += b2a; cB[tt] += b2b; }
}

// RMS over d=128 (64 lanes x 2) for 4 rows.
__device__ __forceinline__ void rms4(float cA[4], float cB[4])
{
  float s[4];
  #pragma unroll
  for (int tt = 0; tt < 4; ++tt) s[tt] = cA[tt]*cA[tt] + cB[tt]*cB[tt];
  #pragma unroll
  for (int off = 32; off; off >>= 1) {
    #pragma unroll
    for (int tt = 0; tt < 4; ++tt) s[tt] += __shfl_xor(s[tt], off);
  }
  #pragma unroll
  for (int tt = 0; tt < 4; ++tt) {
    const float inv = rsqrtf(s[tt] * (1.0f/128.0f) + 1e-6f);
    cA[tt] *= inv; cB[tt] *= inv;
  }
}

// ---------------------------------------------------------------------------
__global__ __launch_bounds__(256) void zero_kernel(float4* __restrict__ p, int n4)
{
  const int i = blockIdx.x * 256 + threadIdx.x;
  if (i < n4) p[i] = make_float4(0.f, 0.f, 0.f, 0.f);
}

// ---------------------------------------------------------------------------
// Node encoder: gather 4x32 embeddings -> MLP 128->256->128 -> RMS -> h.
// ---------------------------------------------------------------------------
__global__ __launch_bounds__(256) void node_enc_kernel(
    const int* __restrict__ ati, const int* __restrict__ aci,
    const int* __restrict__ rci, const int* __restrict__ rsi,
    const float* __restrict__ emb_at, const float* __restrict__ emb_ac,
    const float* __restrict__ emb_rc, const float* __restrict__ emb_ri,
    const float* __restrict__ w1, const float* __restrict__ b1,
    const float* __restrict__ w2, const float* __restrict__ b2,
    float* __restrict__ h, int N)
{
  __shared__ __align__(16) float xs[128*STRIDE];
  __shared__ __align__(16) float hs[256*STRIDE];
  __shared__ int idx_s[4][TILE];
  const int tid = threadIdx.x;
  const int n0 = blockIdx.x * TILE;
  if (tid < TILE) {
    const int n = min(n0 + tid, N - 1);
    idx_s[0][tid] = ati[n]; idx_s[1][tid] = aci[n];
    idx_s[2][tid] = rci[n]; idx_s[3][tid] = rsi[n];
  }
  __syncthreads();
  for (int i = tid; i < TILE*128; i += 256) {
    const int t = i >> 7, k = i & 127;
    const int seg = k >> 5, kk = k & 31;
    const float* tab = (seg == 0) ? emb_at : (seg == 1) ? emb_ac
                     : (seg == 2) ? emb_rc : emb_ri;
    xs[k*STRIDE + t] = tab[idx_s[seg][t]*32 + kk];
  }
  __syncthreads();
  layer1_silu<128>(xs, w1, b1, hs, tid);
  __syncthreads();
  float cA[4], cB[4];
  layer2_bias(hs, w2, b2, tid, cA, cB);
  rms4(cA, cB);
  const int dh = tid & 63, tq = tid >> 6;
  #pragma unroll
  for (int tt = 0; tt < 4; ++tt) {
    const int n = n0 + 4*tq + tt;
    if (n < N) {
      h[(size_t)n*128 + dh]      = cA[tt];
      h[(size_t)n*128 + dh + 64] = cB[tt];
    }
  }
}

// ---------------------------------------------------------------------------
// Edge encoder: geometry -> radial[72] ++ bond[16] -> MLP 88->256->128 -> RMS.
// ---------------------------------------------------------------------------
template<typename ET>
__global__ __launch_bounds__(256) void edge_enc_kernel(
    const float* __restrict__ pos, const float* __restrict__ c_in,
    const int* __restrict__ snd, const int* __restrict__ rcv,
    const int* __restrict__ bnd, const float* __restrict__ emb_bond,
    const float* __restrict__ w1, const float* __restrict__ b1,
    const float* __restrict__ w2, const float* __restrict__ b2,
    ET* __restrict__ e, float* __restrict__ cutb, int E)
{
  __shared__ __align__(16) float xs[88*STRIDE];
  __shared__ __align__(16) float hs[256*STRIDE];
  __shared__ float grbf[TILE][8];
  __shared__ float gylm[TILE][9];
  __shared__ float gcut[TILE];
  __shared__ int   gbond[TILE];
  const int tid = threadIdx.x;
  const int e0 = blockIdx.x * TILE;
  if (tid < TILE) {
    const int ed = min(e0 + tid, E - 1);
    const int sa = snd[ed], ra = rcv[ed];
    const float ci = c_in[0];
    const float vx = (pos[sa*3+0] - pos[ra*3+0]) / ci;
    const float vy = (pos[sa*3+1] - pos[ra*3+1]) / ci;
    const float vz = (pos[sa*3+2] - pos[ra*3+2]) / ci;
    const float r  = sqrtf(vx*vx + vy*vy + vz*vz + 1e-12f);
    const float ir = 1.0f / r;
    const float ux = vx*ir, uy = vy*ir, uz = vz*ir;
    const float PI = 3.14159265358979323846f;
    const float pr = PI * r * 0.2f;
    const float c0 = 0.632455532033675866f;   // sqrt(2/5)
    #pragma unroll
    for (int n = 0; n < 8; ++n)
      grbf[tid][n] = c0 * sinf((float)(n + 1) * pr) * ir;
    const float cv = 0.5f * (cosf(PI * fminf(r, 5.0f) * 0.2f) + 1.0f)
                   * (r < 5.0f ? 1.0f : 0.0f);
    gcut[tid] = cv;
    cutb[ed] = cv;
    const float s3  = 1.7320508075688772f;
    const float s5  = 2.2360679774997896f;
    const float s15 = 3.8729833462074170f;
    gylm[tid][0] = 1.0f;
    gylm[tid][1] = s3*ux; gylm[tid][2] = s3*uy; gylm[tid][3] = s3*uz;
    gylm[tid][4] = s15*ux*uy; gylm[tid][5] = s15*uy*uz;
    gylm[tid][6] = 0.5f*s5*(3.0f*uz*uz - 1.0f);
    gylm[tid][7] = s15*ux*uz;
    gylm[tid][8] = 0.5f*s15*(ux*ux - uy*uy);
    gbond[tid] = bnd[ed];
  }
  __syncthreads();
  for (int i = tid; i < TILE*88; i += 256) {
    const int t = i & 15, k = i >> 4;
    float v;
    if (k < 72) {
      const int n = k / 9, m = k - 9*n;
      v = grbf[t][n] * gylm[t][m] * gcut[t];
    } else {
      v = emb_bond[gbond[t]*16 + (k - 72)];
    }
    xs[k*STRIDE + t] = v;
  }
  __syncthreads();
  layer1_silu<88>(xs, w1, b1, hs, tid);
  __syncthreads();
  float cA[4], cB[4];
  layer2_bias(hs, w2, b2, tid, cA, cB);
  rms4(cA, cB);
  const int dh = tid & 63, tq = tid >> 6;
  #pragma unroll
  for (int tt = 0; tt < 4; ++tt) {
    const int ed = e0 + 4*tq + tt;
    if (ed < E) {
      storeE(&e[(size_t)ed*128 + dh],      cA[tt]);
      storeE(&e[(size_t)ed*128 + dh + 64], cB[tt]);
    }
  }
}

// ---------------------------------------------------------------------------
// Message step: m = MLP([h[s], h[r], e]); g = sigmoid(m.gw+gb)*cut;
// e += m; atomicAdd(agg[rcv], m*g).
// ---------------------------------------------------------------------------
template<typename ET>
__global__ __launch_bounds__(256) void msg_kernel(
    const float* __restrict__ h, ET* __restrict__ e,
    float* __restrict__ agg, const float* __restrict__ cutb,
    const int* __restrict__ snd, const int* __restrict__ rcv,
    const float* __restrict__ w1, const float* __restrict__ b1,
    const float* __restrict__ w2, const float* __restrict__ b2,
    const float* __restrict__ gw, const float* __restrict__ gb,
    int E)
{
  __shared__ __align__(16) float xs[384*STRIDE];
  __shared__ __align__(16) float hs[256*STRIDE];
  __shared__ int   snd_s[TILE], rcv_s[TILE];
  __shared__ float cut_s[TILE];
  const int tid = threadIdx.x;
  const int e0 = blockIdx.x * TILE;
  if (tid < TILE) {
    const int ed = min(e0 + tid, E - 1);
    snd_s[tid] = snd[ed]; rcv_s[tid] = rcv[ed]; cut_s[tid] = cutb[ed];
  }
  __syncthreads();
  for (int i = tid; i < TILE*384; i += 256) {
    const int t = i / 384, k = i - t*384;
    float v;
    if (k < 128)      v = h[(size_t)snd_s[t]*128 + k];
    else if (k < 256) v = h[(size_t)rcv_s[t]*128 + (k - 128)];
    else {
      const int ed = min(e0 + t, E - 1);
      v = loadE(&e[(size_t)ed*128 + (k - 256)]);
    }
    xs[k*STRIDE + t] = v;
  }
  __syncthreads();
  layer1_silu<384>(xs, w1, b1, hs, tid);
  __syncthreads();
  float cA[4], cB[4];
  layer2_bias(hs, w2, b2, tid, cA, cB);
  rms4(cA, cB);
  const int dh = tid & 63, tq = tid >> 6;
  const float gwa = gw[dh], gwb = gw[dh + 64];
  const float gbv = gb[0];
  float gv[4];
  #pragma unroll
  for (int tt = 0; tt < 4; ++tt) gv[tt] = cA[tt]*gwa + cB[tt]*gwb;
  #pragma unroll
  for (int off = 32; off; off >>= 1) {
    #pragma unroll
    for (int tt = 0; tt < 4; ++tt) gv[tt] += __shfl_xor(gv[tt], off);
  }
  #pragma unroll
  for (int tt = 0; tt < 4; ++tt) {
    const int t = 4*tq + tt;
    const int ed = e0 + t;
    if (ed < E) {
      const float g = cut_s[t] / (1.0f + expf(-(gv[tt] + gbv)));
      const float eoA = xs[(256 + dh)*STRIDE + t];       // old e, still in LDS
      const float eoB = xs[(256 + dh + 64)*STRIDE + t];
      storeE(&e[(size_t)ed*128 + dh],      eoA + cA[tt]);
      storeE(&e[(size_t)ed*128 + dh + 64], eoB + cB[tt]);
      const int rv = rcv_s[t];
      atomicAdd(&agg[(size_t)rv*128 + dh],      cA[tt]*g);
      atomicAdd(&agg[(size_t)rv*128 + dh + 64], cB[tt]*g);
    }
  }
}

// ---------------------------------------------------------------------------
// Update step: h += MLP([h, agg]) (256->256->128, RMS).
// ---------------------------------------------------------------------------
__global__ __launch_bounds__(256) void upd_kernel(
    float* __restrict__ h, const float* __restrict__ agg,
    const float* __restrict__ w1, const float* __restrict__ b1,
    const float* __restrict__ w2, const float* __restrict__ b2,
    int N)
{
  __shared__ __align__(16) float xs[256*STRIDE];
  __shared__ __align__(16) float hs[256*STRIDE];
  const int tid = threadIdx.x;
  const int n0 = blockIdx.x * TILE;
  for (int i = tid; i < TILE*256; i += 256) {
    const int t = i >> 8, k = i & 255;
    const int n = min(n0 + t, N - 1);
    const float v = (k < 128) ? h[(size_t)n*128 + k]
                              : agg[(size_t)n*128 + (k - 128)];
    xs[k*STRIDE + t] = v;
  }
  __syncthreads();
  layer1_silu<256>(xs, w1, b1, hs, tid);
  __syncthreads();
  float cA[4], cB[4];
  layer2_bias(hs, w2, b2, tid, cA, cB);
  rms4(cA, cB);
  const int dh = tid & 63, tq = tid >> 6;
  #pragma unroll
  for (int tt = 0; tt < 4; ++tt) {
    const int t = 4*tq + tt;
    const int n = n0 + t;
    if (n < N) {
      h[(size_t)n*128 + dh]      = xs[dh*STRIDE + t] + cA[tt];
      h[(size_t)n*128 + dh + 64] = xs[(dh + 64)*STRIDE + t] + cB[tt];
    }
  }
}

// ---------------------------------------------------------------------------
// Head: out = silu(h @ w1 + b1) @ w2 + b2.
// ---------------------------------------------------------------------------
__global__ __launch_bounds__(256) void head_kernel(
    const float* __restrict__ h,
    const float* __restrict__ w1, const float* __restrict__ b1,
    const float* __restrict__ w2, const float* __restrict__ b2,
    float* __restrict__ out, int N)
{
  __shared__ __align__(16) float xs[128*STRIDE];
  __shared__ __align__(16) float hs[256*STRIDE];
  const int tid = threadIdx.x;
  const int n0 = blockIdx.x * TILE;
  for (int i = tid; i < TILE*128; i += 256) {
    const int t = i >> 7, k = i & 127;
    const int n = min(n0 + t, N - 1);
    xs[k*STRIDE + t] = h[(size_t)n*128 + k];
  }
  __syncthreads();
  layer1_silu<128>(xs, w1, b1, hs, tid);
  __syncthreads();
  if (tid < 48) {
    const int t = tid / 3, o = tid - 3*(tid/3);
    float acc = b2[o];
    for (int k = 0; k < 256; ++k)
      acc = fmaf(hs[k*STRIDE + t], w2[k*3 + o], acc);
    const int n = n0 + t;
    if (n < N) out[(size_t)n*3 + o] = acc;
  }
}

// ---------------------------------------------------------------------------
template<typename ET>
static void run_pipeline(const float* pos, const float* c_in,
    const int* ati, const int* aci, const int* rci, const int* rsi,
    const int* snd, const int* rcv, const int* bnd,
    const float* emb_at, const float* emb_ac, const float* emb_rc,
    const float* emb_ri, const float* emb_bond,
    const float* nenc_w1, const float* nenc_b1, const float* nenc_w2, const float* nenc_b2,
    const float* eenc_w1, const float* eenc_b1, const float* eenc_w2, const float* eenc_b2,
    const float* msg_w1, const float* msg_b1, const float* msg_w2, const float* msg_b2,
    const float* gate_w, const float* gate_b,
    const float* upd_w1, const float* upd_b1, const float* upd_w2, const float* upd_b2,
    const float* head_w1, const float* head_b1, const float* head_w2, const float* head_b2,
    float* hbuf, ET* ebuf, float* aggbuf, float* cutbuf,
    float* out, int N, int E, hipStream_t stream)
{
  const int nb_n = (N + TILE - 1) / TILE;
  const int nb_e = (E + TILE - 1) / TILE;
  const int n4   = N * 128 / 4;

  node_enc_kernel<<<nb_n, 256, 0, stream>>>(
      ati, aci, rci, rsi, emb_at, emb_ac, emb_rc, emb_ri,
      nenc_w1, nenc_b1, nenc_w2, nenc_b2, hbuf, N);

  edge_enc_kernel<ET><<<nb_e, 256, 0, stream>>>(
      pos, c_in, snd, rcv, bnd, emb_bond,
      eenc_w1, eenc_b1, eenc_w2, eenc_b2, ebuf, cutbuf, E);

  for (int s = 0; s < 4; ++s) {
    zero_kernel<<<(n4 + 255) / 256, 256, 0, stream>>>((float4*)aggbuf, n4);
    msg_kernel<ET><<<nb_e, 256, 0, stream>>>(
        hbuf, ebuf, aggbuf, cutbuf, snd, rcv,
        msg_w1 + (size_t)s * 384 * 256, msg_b1 + (size_t)s * 256,
        msg_w2 + (size_t)s * 256 * 128, msg_b2 + (size_t)s * 128,
        gate_w + (size_t)s * 128, gate_b + s, E);
    upd_kernel<<<nb_n, 256, 0, stream>>>(
        hbuf, aggbuf,
        upd_w1 + (size_t)s * 256 * 256, upd_b1 + (size_t)s * 256,
        upd_w2 + (size_t)s * 256 * 128, upd_b2 + (size_t)s * 128, N);
  }

  head_kernel<<<nb_n, 256, 0, stream>>>(
      hbuf, head_w1, head_b1, head_w2, head_b2, out, N);
}

extern "C" void kernel_launch(void* const* d_in, const int* in_sizes, int n_in,
                              void* d_out, int out_size, void* d_ws, size_t ws_size,
                              hipStream_t stream)
{
  const float* pos      = (const float*)d_in[0];
  const float* c_in     = (const float*)d_in[1];
  const int*   ati      = (const int*)d_in[2];
  const int*   aci      = (const int*)d_in[3];
  const int*   rci      = (const int*)d_in[4];
  const int*   rsi      = (const int*)d_in[5];
  const int*   snd      = (const int*)d_in[6];
  const int*   rcv      = (const int*)d_in[7];
  const int*   bnd      = (const int*)d_in[8];
  const float* emb_at   = (const float*)d_in[9];
  const float* emb_ac   = (const float*)d_in[10];
  const float* emb_rc   = (const float*)d_in[11];
  const float* emb_ri   = (const float*)d_in[12];
  const float* emb_bond = (const float*)d_in[13];
  const float* nenc_w1  = (const float*)d_in[14];
  const float* nenc_b1  = (const float*)d_in[15];
  const float* nenc_w2  = (const float*)d_in[16];
  const float* nenc_b2  = (const float*)d_in[17];
  const float* eenc_w1  = (const float*)d_in[18];
  const float* eenc_b1  = (const float*)d_in[19];
  const float* eenc_w2  = (const float*)d_in[20];
  const float* eenc_b2  = (const float*)d_in[21];
  const float* msg_w1   = (const float*)d_in[22];
  const float* msg_b1   = (const float*)d_in[23];
  const float* msg_w2   = (const float*)d_in[24];
  const float* msg_b2   = (const float*)d_in[25];
  const float* gate_w   = (const float*)d_in[26];
  const float* gate_b   = (const float*)d_in[27];
  const float* upd_w1   = (const float*)d_in[28];
  const float* upd_b1   = (const float*)d_in[29];
  const float* upd_w2   = (const float*)d_in[30];
  const float* upd_b2   = (const float*)d_in[31];
  const float* head_w1  = (const float*)d_in[32];
  const float* head_b1  = (const float*)d_in[33];
  const float* head_w2  = (const float*)d_in[34];
  const float* head_b2  = (const float*)d_in[35];

  const int N = in_sizes[0] / 3;
  const int E = in_sizes[6];

  // Small fp32 buffers first, big e-buffer last; e is fp32 if it fits, else bf16.
  char* ws = (char*)d_ws;
  float* hbuf   = (float*)ws;                  ws += (size_t)N * 128 * sizeof(float);
  float* aggbuf = (float*)ws;                  ws += (size_t)N * 128 * sizeof(float);
  float* cutbuf = (float*)ws;                  ws += (size_t)E * sizeof(float);
  const size_t base = (size_t)(ws - (char*)d_ws);
  const size_t need_f32 = base + (size_t)E * 128 * sizeof(float);

  if (ws_size >= need_f32) {
    float* ebuf = (float*)ws;
    run_pipeline<float>(pos, c_in, ati, aci, rci, rsi, snd, rcv, bnd,
        emb_at, emb_ac, emb_rc, emb_ri, emb_bond,
        nenc_w1, nenc_b1, nenc_w2, nenc_b2,
        eenc_w1, eenc_b1, eenc_w2, eenc_b2,
        msg_w1, msg_b1, msg_w2, msg_b2, gate_w, gate_b,
        upd_w1, upd_b1, upd_w2, upd_b2,
        head_w1, head_b1, head_w2, head_b2,
        hbuf, ebuf, aggbuf, cutbuf, (float*)d_out, N, E, stream);
  } else {
    __hip_bfloat16* ebuf = (__hip_bfloat16*)ws;
    run_pipeline<__hip_bfloat16>(pos, c_in, ati, aci, rci, rsi, snd, rcv, bnd,
        emb_at, emb_ac, emb_rc, emb_ri, emb_bond,
        nenc_w1, nenc_b1, nenc_w2, nenc_b2,
        eenc_w1, eenc_b1, eenc_w2, eenc_b2,
        msg_w1, msg_b1, msg_w2, msg_b2, gate_w, gate_b,
        upd_w1, upd_b1, upd_w2, upd_b2,
        head_w1, head_b1, head_w2, head_b2,
        hbuf, ebuf, aggbuf, cutbuf, (float*)d_out, N, E, stream);
  }
}

// Round 3
// 2731.498 us; speedup vs baseline: 4.6373x; 4.6373x over previous
//
#include <hip/hip_runtime.h>
#include <hip/hip_bf16.h>
#include <math.h>

// ---------------------------------------------------------------------------
// MoleculeGNS — MFMA bf16 pipeline (edge_enc / msg / upd) + fp32 node/head.
// Fallback to the proven round-2 fp32-VALU pipeline if ws_size is too small.
//
// MFMA tile geometry (all three MFMA kernels):
//   block = 256 threads (4 waves), MT=32 rows/block.
//   X1 (LDS, bf16): [32][K1pad] with 16B-granule XOR swizzle (g ^= r&7).
//   layer1: [32,K1]@[K1,256]+b1, silu -> hsm LDS [32][256] bf16 (swizzled).
//     wave w: cols 64w..64w+63 (4 n-frags), rows all 32 (2 m-frags).
//   layer2: [32,256]@[256,128]+b2 -> acc2; wave w: cols 32w..32w+31.
//   Weights pre-packed fragment-major bf16: B-frag = 1 coalesced 16B/lane load.
//   MFMA 16x16x32 bf16: A lane: row=l&15,k0=(l>>4)*8 (8 contig);
//   B lane: col=l&15,k0=(l>>4)*8; D lane: col=l&15,row=(l>>4)*4+q (m89).
// ---------------------------------------------------------------------------

#define TILE   16
#define STRIDE 20

using short8 = __attribute__((ext_vector_type(8))) short;
using f32x4  = __attribute__((ext_vector_type(4))) float;

__device__ __forceinline__ float silu_f(float x) {
  return x / (1.0f + expf(-x));
}
__device__ __forceinline__ unsigned short f2b(float x) {
  union { float f; unsigned u; } v; v.f = x;
  unsigned r = v.u + 0x7fffu + ((v.u >> 16) & 1u);
  return (unsigned short)(r >> 16);
}
__device__ __forceinline__ float b2f(unsigned short h) {
  union { unsigned u; float f; } v; v.u = ((unsigned)h) << 16;
  return v.f;
}

// ---------------------------------------------------------------------------
// Weight pack: src row-major [Kreal][N=NF*16] fp32 -> frag-major bf16:
// dst[((nf*KS+kk)*64+l)*8+j] = src[kk*32+(l>>4)*8+j][nf*16+(l&15)], 0 if k>=Kreal
// ---------------------------------------------------------------------------
__global__ __launch_bounds__(256) void pack_w_kernel(
    const float* __restrict__ src, unsigned short* __restrict__ dst,
    int Kreal, int KS, int NF)
{
  const int N = NF * 16;
  const int total = NF * KS * 512;
  for (int idx = blockIdx.x * 256 + threadIdx.x; idx < total; idx += gridDim.x * 256) {
    const int nf  = idx / (KS * 512);
    const int rem = idx - nf * (KS * 512);
    const int kk  = rem >> 9;
    const int p   = rem & 511;
    const int l   = p >> 3, j = p & 7;
    const int c   = nf * 16 + (l & 15);
    const int k   = kk * 32 + ((l >> 4) << 3) + j;
    dst[idx] = (k < Kreal) ? f2b(src[(size_t)k * N + c]) : (unsigned short)0;
  }
}

// ---------------------------------------------------------------------------
// MFMA layer 1: X1[32][KS1*32] (swizzled bf16 LDS) @ w1p -> silu -> hsm.
// ---------------------------------------------------------------------------
template<int KS1>
__device__ __forceinline__ void mfma_l1(const unsigned short* __restrict__ x1,
                                        const unsigned short* __restrict__ w1p,
                                        const float* __restrict__ b1,
                                        unsigned short* __restrict__ hsm, int tid)
{
  const int w  = tid >> 6;
  const int l  = tid & 63;
  const int lr = l & 15;
  const int lk = (l >> 4) << 3;
  const int RS = KS1 * 32;
  f32x4 acc[8];
  const f32x4 zz = {0.f, 0.f, 0.f, 0.f};
  #pragma unroll
  for (int i = 0; i < 8; ++i) acc[i] = zz;

  for (int kk = 0; kk < KS1; ++kk) {
    short8 af[2];
    #pragma unroll
    for (int mf = 0; mf < 2; ++mf) {
      const int r = mf * 16 + lr;
      const int k = kk * 32 + lk;
      af[mf] = *(const short8*)&x1[r * RS + ((((k >> 3) ^ (r & 7))) << 3)];
    }
    #pragma unroll
    for (int nf = 0; nf < 4; ++nf) {
      const int nfg = w * 4 + nf;
      const short8 bf = *(const short8*)&w1p[(size_t)(((nfg * KS1) + kk) * 64 + l) * 8];
      #pragma unroll
      for (int mf = 0; mf < 2; ++mf)
        acc[mf * 4 + nf] = __builtin_amdgcn_mfma_f32_16x16x32_bf16(af[mf], bf, acc[mf * 4 + nf], 0, 0, 0);
    }
  }
  // bias + silu + bf16 store to hsm (swizzled)
  #pragma unroll
  for (int nf = 0; nf < 4; ++nf) {
    const int c = (w * 4 + nf) * 16 + lr;
    const float bias = b1[c];
    #pragma unroll
    for (int mf = 0; mf < 2; ++mf) {
      #pragma unroll
      for (int q = 0; q < 4; ++q) {
        const int r = mf * 16 + ((l >> 4) << 2) + q;
        const float v = silu_f(acc[mf * 4 + nf][q] + bias);
        hsm[r * 256 + (((c >> 3) ^ (r & 7)) << 3) + (c & 7)] = f2b(v);
      }
    }
  }
}

// ---------------------------------------------------------------------------
// MFMA layer 2: hsm[32][256] @ w2p [256,128] + b2 -> acc2[4] (wave cols 32w..).
// ---------------------------------------------------------------------------
__device__ __forceinline__ void mfma_l2(const unsigned short* __restrict__ hsm,
                                        const unsigned short* __restrict__ w2p,
                                        const float* __restrict__ b2,
                                        int tid, f32x4 acc2[4])
{
  const int w  = tid >> 6;
  const int l  = tid & 63;
  const int lr = l & 15;
  const int lk = (l >> 4) << 3;
  const f32x4 zz = {0.f, 0.f, 0.f, 0.f};
  #pragma unroll
  for (int i = 0; i < 4; ++i) acc2[i] = zz;

  for (int kk = 0; kk < 8; ++kk) {
    short8 af[2];
    #pragma unroll
    for (int mf = 0; mf < 2; ++mf) {
      const int r = mf * 16 + lr;
      const int k = kk * 32 + lk;
      af[mf] = *(const short8*)&hsm[r * 256 + (((k >> 3) ^ (r & 7)) << 3)];
    }
    #pragma unroll
    for (int nf2 = 0; nf2 < 2; ++nf2) {
      const int nfg = w * 2 + nf2;
      const short8 bf = *(const short8*)&w2p[(size_t)(((nfg * 8) + kk) * 64 + l) * 8];
      #pragma unroll
      for (int mf = 0; mf < 2; ++mf)
        acc2[mf * 2 + nf2] = __builtin_amdgcn_mfma_f32_16x16x32_bf16(af[mf], bf, acc2[mf * 2 + nf2], 0, 0, 0);
    }
  }
  #pragma unroll
  for (int nf2 = 0; nf2 < 2; ++nf2) {
    const float bias = b2[(w * 2 + nf2) * 16 + lr];
    #pragma unroll
    for (int mf = 0; mf < 2; ++mf) {
      #pragma unroll
      for (int q = 0; q < 4; ++q) acc2[mf * 2 + nf2][q] += bias;
    }
  }
}

// ---------------------------------------------------------------------------
// RMS over d=128 for 32 rows: 16-lane shuffle reduce + LDS atomics.
// rsum must be pre-zeroed; contains sum after internal barrier.
// ---------------------------------------------------------------------------
__device__ __forceinline__ void rms_reduce(const f32x4 acc2[4], float* rsum,
                                           int tid, float mval[2][2][4])
{
  const int l = tid & 63;
  #pragma unroll
  for (int mf = 0; mf < 2; ++mf) {
    #pragma unroll
    for (int q = 0; q < 4; ++q) {
      float s = acc2[mf * 2][q] * acc2[mf * 2][q]
              + acc2[mf * 2 + 1][q] * acc2[mf * 2 + 1][q];
      s += __shfl_xor(s, 1); s += __shfl_xor(s, 2);
      s += __shfl_xor(s, 4); s += __shfl_xor(s, 8);
      if ((l & 15) == 0)
        atomicAdd(&rsum[mf * 16 + ((l >> 4) << 2) + q], s);
    }
  }
  __syncthreads();
  #pragma unroll
  for (int mf = 0; mf < 2; ++mf) {
    #pragma unroll
    for (int q = 0; q < 4; ++q) {
      const int r = mf * 16 + ((l >> 4) << 2) + q;
      const float inv = rsqrtf(rsum[r] * (1.0f / 128.0f) + 1e-6f);
      #pragma unroll
      for (int nf2 = 0; nf2 < 2; ++nf2)
        mval[mf][nf2][q] = acc2[mf * 2 + nf2][q] * inv;
    }
  }
}

// ---------------------------------------------------------------------------
// Edge encoder (MFMA): geometry -> X1[32][128] -> MLP -> RMS -> e (bf16), cut.
// ---------------------------------------------------------------------------
__global__ __launch_bounds__(256, 3) void edge_enc_mfma(
    const float* __restrict__ pos, const float* __restrict__ c_in,
    const int* __restrict__ snd, const int* __restrict__ rcv,
    const int* __restrict__ bnd, const float* __restrict__ embb,
    const unsigned short* __restrict__ w1p, const float* __restrict__ b1,
    const unsigned short* __restrict__ w2p, const float* __restrict__ b2,
    unsigned short* __restrict__ e_g, float* __restrict__ cutb, int E)
{
  __shared__ __align__(16) unsigned short x1[32 * 128];
  __shared__ __align__(16) unsigned short hsm[32 * 256];
  __shared__ float grbf[32][8];
  __shared__ float gylm[32][9];
  __shared__ float gcut[32];
  __shared__ int   gbond[32];
  __shared__ float rsum[32];
  const int tid = threadIdx.x;
  const int e0  = blockIdx.x * 32;

  if (tid < 32) {
    rsum[tid] = 0.f;
    const int ed = min(e0 + tid, E - 1);
    const int sa = snd[ed], ra = rcv[ed];
    const float ci = c_in[0];
    const float vx = (pos[sa * 3 + 0] - pos[ra * 3 + 0]) / ci;
    const float vy = (pos[sa * 3 + 1] - pos[ra * 3 + 1]) / ci;
    const float vz = (pos[sa * 3 + 2] - pos[ra * 3 + 2]) / ci;
    const float r  = sqrtf(vx * vx + vy * vy + vz * vz + 1e-12f);
    const float ir = 1.0f / r;
    const float ux = vx * ir, uy = vy * ir, uz = vz * ir;
    const float PI = 3.14159265358979323846f;
    const float pr = PI * r * 0.2f;
    const float c0 = 0.632455532033675866f;   // sqrt(2/5)
    #pragma unroll
    for (int n = 0; n < 8; ++n)
      grbf[tid][n] = c0 * sinf((float)(n + 1) * pr) * ir;
    const float cv = 0.5f * (cosf(PI * fminf(r, 5.0f) * 0.2f) + 1.0f)
                   * (r < 5.0f ? 1.0f : 0.0f);
    gcut[tid] = cv;
    if (e0 + tid < E) cutb[e0 + tid] = cv;
    const float s3  = 1.7320508075688772f;
    const float s5  = 2.2360679774997896f;
    const float s15 = 3.8729833462074170f;
    gylm[tid][0] = 1.0f;
    gylm[tid][1] = s3 * ux; gylm[tid][2] = s3 * uy; gylm[tid][3] = s3 * uz;
    gylm[tid][4] = s15 * ux * uy; gylm[tid][5] = s15 * uy * uz;
    gylm[tid][6] = 0.5f * s5 * (3.0f * uz * uz - 1.0f);
    gylm[tid][7] = s15 * ux * uz;
    gylm[tid][8] = 0.5f * s15 * (ux * ux - uy * uy);
    gbond[tid] = bnd[ed];
  }
  __syncthreads();
  for (int i = tid; i < 32 * 16; i += 256) {
    const int r = i >> 4, g = i & 15;
    union { short8 v; unsigned short u[8]; } t;
    #pragma unroll
    for (int j = 0; j < 8; ++j) {
      const int k = g * 8 + j;
      float v;
      if (k < 72) { const int n = k / 9, mm = k - 9 * n; v = grbf[r][n] * gylm[r][mm] * gcut[r]; }
      else if (k < 88) v = embb[gbond[r] * 16 + (k - 72)];
      else v = 0.f;
      t.u[j] = f2b(v);
    }
    *(short8*)&x1[r * 128 + ((g ^ (r & 7)) << 3)] = t.v;
  }
  __syncthreads();
  mfma_l1<4>(x1, w1p, b1, hsm, tid);
  __syncthreads();
  f32x4 acc2[4];
  mfma_l2(hsm, w2p, b2, tid, acc2);
  float mval[2][2][4];
  rms_reduce(acc2, rsum, tid, mval);
  const int l = tid & 63, w = tid >> 6, lr = l & 15;
  #pragma unroll
  for (int mf = 0; mf < 2; ++mf) {
    #pragma unroll
    for (int q = 0; q < 4; ++q) {
      const int r = mf * 16 + ((l >> 4) << 2) + q;
      const int ed = e0 + r;
      if (ed < E) {
        #pragma unroll
        for (int nf2 = 0; nf2 < 2; ++nf2) {
          const int c2 = (w * 2 + nf2) * 16 + lr;
          e_g[(size_t)ed * 128 + c2] = f2b(mval[mf][nf2][q]);
        }
      }
    }
  }
}

// ---------------------------------------------------------------------------
// Message step (MFMA): X1 = [h_s | h_r | e] -> MLP -> RMS -> gate, e+=m, agg.
// ---------------------------------------------------------------------------
__global__ __launch_bounds__(256, 3) void msg_mfma(
    const float* __restrict__ h, unsigned short* __restrict__ e_g,
    float* __restrict__ agg, const float* __restrict__ cutb,
    const int* __restrict__ snd, const int* __restrict__ rcv,
    const unsigned short* __restrict__ w1p, const float* __restrict__ b1,
    const unsigned short* __restrict__ w2p, const float* __restrict__ b2,
    const float* __restrict__ gw, const float* __restrict__ gb, int E)
{
  __shared__ __align__(16) unsigned short x1[32 * 384];
  __shared__ __align__(16) unsigned short hsm[32 * 256];
  __shared__ int   snd_s[32], rcv_s[32];
  __shared__ float cut_s[32];
  __shared__ float rsum[32], gsum[32];
  const int tid = threadIdx.x;
  const int e0  = blockIdx.x * 32;

  if (tid < 32) {
    rsum[tid] = 0.f; gsum[tid] = 0.f;
    const int ed = min(e0 + tid, E - 1);
    snd_s[tid] = snd[ed]; rcv_s[tid] = rcv[ed]; cut_s[tid] = cutb[ed];
  }
  __syncthreads();
  for (int i = tid; i < 32 * 48; i += 256) {
    const int r = i / 48, g = i - r * 48;
    union { short8 v; unsigned short u[8]; } t;
    if (g < 32) {
      const int node = (g < 16) ? snd_s[r] : rcv_s[r];
      const int k0 = (g & 15) * 8;
      const float4 f0 = *(const float4*)&h[(size_t)node * 128 + k0];
      const float4 f1 = *(const float4*)&h[(size_t)node * 128 + k0 + 4];
      t.u[0] = f2b(f0.x); t.u[1] = f2b(f0.y); t.u[2] = f2b(f0.z); t.u[3] = f2b(f0.w);
      t.u[4] = f2b(f1.x); t.u[5] = f2b(f1.y); t.u[6] = f2b(f1.z); t.u[7] = f2b(f1.w);
    } else {
      const int ed = min(e0 + r, E - 1);
      t.v = *(const short8*)&e_g[(size_t)ed * 128 + (g - 32) * 8];
    }
    *(short8*)&x1[r * 384 + ((g ^ (r & 7)) << 3)] = t.v;
  }
  __syncthreads();
  mfma_l1<12>(x1, w1p, b1, hsm, tid);
  __syncthreads();
  f32x4 acc2[4];
  mfma_l2(hsm, w2p, b2, tid, acc2);
  float mval[2][2][4];
  rms_reduce(acc2, rsum, tid, mval);

  const int l = tid & 63, w = tid >> 6, lr = l & 15;
  // gate partial: dot(m, gw) per row
  const float gw0 = gw[(w * 2 + 0) * 16 + lr];
  const float gw1 = gw[(w * 2 + 1) * 16 + lr];
  #pragma unroll
  for (int mf = 0; mf < 2; ++mf) {
    #pragma unroll
    for (int q = 0; q < 4; ++q) {
      float p = mval[mf][0][q] * gw0 + mval[mf][1][q] * gw1;
      p += __shfl_xor(p, 1); p += __shfl_xor(p, 2);
      p += __shfl_xor(p, 4); p += __shfl_xor(p, 8);
      if ((l & 15) == 0)
        atomicAdd(&gsum[mf * 16 + ((l >> 4) << 2) + q], p);
    }
  }
  __syncthreads();
  const float gbv = gb[0];
  #pragma unroll
  for (int mf = 0; mf < 2; ++mf) {
    #pragma unroll
    for (int q = 0; q < 4; ++q) {
      const int r = mf * 16 + ((l >> 4) << 2) + q;
      const int ed = e0 + r;
      if (ed < E) {
        const float gr = cut_s[r] / (1.0f + expf(-(gsum[r] + gbv)));
        const int rv = rcv_s[r];
        #pragma unroll
        for (int nf2 = 0; nf2 < 2; ++nf2) {
          const int c2 = (w * 2 + nf2) * 16 + lr;
          const float m = mval[mf][nf2][q];
          const int k = 256 + c2;
          const float eo = b2f(x1[r * 384 + (((k >> 3) ^ (r & 7)) << 3) + (k & 7)]);
          e_g[(size_t)ed * 128 + c2] = f2b(eo + m);
          atomicAdd(&agg[(size_t)rv * 128 + c2], m * gr);
        }
      }
    }
  }
}

// ---------------------------------------------------------------------------
// Update step (MFMA): X1 = [h | agg] -> MLP -> RMS -> h += m  (h fp32).
// ---------------------------------------------------------------------------
__global__ __launch_bounds__(256, 3) void upd_mfma(
    float* __restrict__ h, const float* __restrict__ agg,
    const unsigned short* __restrict__ w1p, const float* __restrict__ b1,
    const unsigned short* __restrict__ w2p, const float* __restrict__ b2,
    int N)
{
  __shared__ __align__(16) unsigned short x1[32 * 256];
  __shared__ __align__(16) unsigned short hsm[32 * 256];
  __shared__ float rsum[32];
  const int tid = threadIdx.x;
  const int n0  = blockIdx.x * 32;
  if (tid < 32) rsum[tid] = 0.f;
  __syncthreads();
  for (int i = tid; i < 32 * 32; i += 256) {
    const int r = i >> 5, g = i & 31;
    const int n = min(n0 + r, N - 1);
    const float* src = (g < 16) ? &h[(size_t)n * 128 + g * 8]
                                : &agg[(size_t)n * 128 + (g - 16) * 8];
    const float4 f0 = *(const float4*)src;
    const float4 f1 = *(const float4*)(src + 4);
    union { short8 v; unsigned short u[8]; } t;
    t.u[0] = f2b(f0.x); t.u[1] = f2b(f0.y); t.u[2] = f2b(f0.z); t.u[3] = f2b(f0.w);
    t.u[4] = f2b(f1.x); t.u[5] = f2b(f1.y); t.u[6] = f2b(f1.z); t.u[7] = f2b(f1.w);
    *(short8*)&x1[r * 256 + ((g ^ (r & 7)) << 3)] = t.v;
  }
  __syncthreads();
  mfma_l1<8>(x1, w1p, b1, hsm, tid);
  __syncthreads();
  f32x4 acc2[4];
  mfma_l2(hsm, w2p, b2, tid, acc2);
  float mval[2][2][4];
  rms_reduce(acc2, rsum, tid, mval);
  const int l = tid & 63, w = tid >> 6, lr = l & 15;
  #pragma unroll
  for (int mf = 0; mf < 2; ++mf) {
    #pragma unroll
    for (int q = 0; q < 4; ++q) {
      const int r = mf * 16 + ((l >> 4) << 2) + q;
      const int n = n0 + r;
      if (n < N) {
        #pragma unroll
        for (int nf2 = 0; nf2 < 2; ++nf2) {
          const int c2 = (w * 2 + nf2) * 16 + lr;
          h[(size_t)n * 128 + c2] += mval[mf][nf2][q];
        }
      }
    }
  }
}

// ===========================================================================
// Round-2 fp32 pipeline (fallback + node/head kernels).
// ===========================================================================

__device__ __forceinline__ float loadE(const float* p)          { return *p; }
__device__ __forceinline__ float loadE(const __hip_bfloat16* p) { return __bfloat162float(*p); }
__device__ __forceinline__ void  storeE(float* p, float v)          { *p = v; }
__device__ __forceinline__ void  storeE(__hip_bfloat16* p, float v) { *p = __float2bfloat16(v); }

template<int K1>
__device__ __forceinline__ void layer1_silu(const float* __restrict__ xs,
                                            const float* __restrict__ w1,
                                            const float* __restrict__ b1,
                                            float* __restrict__ hs, int tid)
{
  const int jh = tid & 127;
  const int tp = tid >> 7;
  const int tbase = 8 * tp;
  float a[8] = {0,0,0,0,0,0,0,0};
  float b[8] = {0,0,0,0,0,0,0,0};
  const float* wp = w1 + jh;
  for (int k = 0; k < K1; ++k) {
    const float4 x0 = *(const float4*)&xs[k*STRIDE + tbase];
    const float4 x1 = *(const float4*)&xs[k*STRIDE + tbase + 4];
    const float wa = wp[k*256];
    const float wb = wp[k*256 + 128];
    a[0] = fmaf(x0.x, wa, a[0]); a[1] = fmaf(x0.y, wa, a[1]);
    a[2] = fmaf(x0.z, wa, a[2]); a[3] = fmaf(x0.w, wa, a[3]);
    a[4] = fmaf(x1.x, wa, a[4]); a[5] = fmaf(x1.y, wa, a[5]);
    a[6] = fmaf(x1.z, wa, a[6]); a[7] = fmaf(x1.w, wa, a[7]);
    b[0] = fmaf(x0.x, wb, b[0]); b[1] = fmaf(x0.y, wb, b[1]);
    b[2] = fmaf(x0.z, wb, b[2]); b[3] = fmaf(x0.w, wb, b[3]);
    b[4] = fmaf(x1.x, wb, b[4]); b[5] = fmaf(x1.y, wb, b[5]);
    b[6] = fmaf(x1.z, wb, b[6]); b[7] = fmaf(x1.w, wb, b[7]);
  }
  const float ba = b1[jh];
  const float bb = b1[jh + 128];
  float4 oa0, oa1, ob0, ob1;
  oa0.x = silu_f(a[0] + ba); oa0.y = silu_f(a[1] + ba);
  oa0.z = silu_f(a[2] + ba); oa0.w = silu_f(a[3] + ba);
  oa1.x = silu_f(a[4] + ba); oa1.y = silu_f(a[5] + ba);
  oa1.z = silu_f(a[6] + ba); oa1.w = silu_f(a[7] + ba);
  ob0.x = silu_f(b[0] + bb); ob0.y = silu_f(b[1] + bb);
  ob0.z = silu_f(b[2] + bb); ob0.w = silu_f(b[3] + bb);
  ob1.x = silu_f(b[4] + bb); ob1.y = silu_f(b[5] + bb);
  ob1.z = silu_f(b[6] + bb); ob1.w = silu_f(b[7] + bb);
  *(float4*)&hs[jh*STRIDE + tbase]           = oa0;
  *(float4*)&hs[jh*STRIDE + tbase + 4]       = oa1;
  *(float4*)&hs[(jh+128)*STRIDE + tbase]     = ob0;
  *(float4*)&hs[(jh+128)*STRIDE + tbase + 4] = ob1;
}

__device__ __forceinline__ void layer2_bias(const float* __restrict__ hs,
                                            const float* __restrict__ w2,
                                            const float* __restrict__ b2,
                                            int tid, float cA[4], float cB[4])
{
  const int dh = tid & 63;
  const int tq = tid >> 6;
  const int tbase = 4 * tq;
  cA[0]=cA[1]=cA[2]=cA[3]=0.0f;
  cB[0]=cB[1]=cB[2]=cB[3]=0.0f;
  const float* wp = w2 + dh;
  for (int k = 0; k < 256; ++k) {
    const float4 hv = *(const float4*)&hs[k*STRIDE + tbase];
    const float wa = wp[k*128];
    const float wb = wp[k*128 + 64];
    cA[0] = fmaf(hv.x, wa, cA[0]); cA[1] = fmaf(hv.y, wa, cA[1]);
    cA[2] = fmaf(hv.z, wa, cA[2]); cA[3] = fmaf(hv.w, wa, cA[3]);
    cB[0] = fmaf(hv.x, wb, cB[0]); cB[1] = fmaf(hv.y, wb, cB[1]);
    cB[2] = fmaf(hv.z, wb, cB[2]); cB[3] = fmaf(hv.w, wb, cB[3]);
  }
  const float b2a = b2[dh];
  const float b2b = b2[dh + 64];
  #pragma unroll
  for (int tt = 0; tt < 4; ++tt) { cA[tt] += b2a; cB[tt] += b2b; }
}

__device__ __forceinline__ void rms4(float cA[4], float cB[4])
{
  float s[4];
  #pragma unroll
  for (int tt = 0; tt < 4; ++tt) s[tt] = cA[tt]*cA[tt] + cB[tt]*cB[tt];
  #pragma unroll
  for (int off = 32; off; off >>= 1) {
    #pragma unroll
    for (int tt = 0; tt < 4; ++tt) s[tt] += __shfl_xor(s[tt], off);
  }
  #pragma unroll
  for (int tt = 0; tt < 4; ++tt) {
    const float inv = rsqrtf(s[tt] * (1.0f/128.0f) + 1e-6f);
    cA[tt] *= inv; cB[tt] *= inv;
  }
}

__global__ __launch_bounds__(256) void zero_kernel(float4* __restrict__ p, int n4)
{
  const int i = blockIdx.x * 256 + threadIdx.x;
  if (i < n4) p[i] = make_float4(0.f, 0.f, 0.f, 0.f);
}

__global__ __launch_bounds__(256) void node_enc_kernel(
    const int* __restrict__ ati, const int* __restrict__ aci,
    const int* __restrict__ rci, const int* __restrict__ rsi,
    const float* __restrict__ emb_at, const float* __restrict__ emb_ac,
    const float* __restrict__ emb_rc, const float* __restrict__ emb_ri,
    const float* __restrict__ w1, const float* __restrict__ b1,
    const float* __restrict__ w2, const float* __restrict__ b2,
    float* __restrict__ h, int N)
{
  __shared__ __align__(16) float xs[128*STRIDE];
  __shared__ __align__(16) float hs[256*STRIDE];
  __shared__ int idx_s[4][TILE];
  const int tid = threadIdx.x;
  const int n0 = blockIdx.x * TILE;
  if (tid < TILE) {
    const int n = min(n0 + tid, N - 1);
    idx_s[0][tid] = ati[n]; idx_s[1][tid] = aci[n];
    idx_s[2][tid] = rci[n]; idx_s[3][tid] = rsi[n];
  }
  __syncthreads();
  for (int i = tid; i < TILE*128; i += 256) {
    const int t = i >> 7, k = i & 127;
    const int seg = k >> 5, kk = k & 31;
    const float* tab = (seg == 0) ? emb_at : (seg == 1) ? emb_ac
                     : (seg == 2) ? emb_rc : emb_ri;
    xs[k*STRIDE + t] = tab[idx_s[seg][t]*32 + kk];
  }
  __syncthreads();
  layer1_silu<128>(xs, w1, b1, hs, tid);
  __syncthreads();
  float cA[4], cB[4];
  layer2_bias(hs, w2, b2, tid, cA, cB);
  rms4(cA, cB);
  const int dh = tid & 63, tq = tid >> 6;
  #pragma unroll
  for (int tt = 0; tt < 4; ++tt) {
    const int n = n0 + 4*tq + tt;
    if (n < N) {
      h[(size_t)n*128 + dh]      = cA[tt];
      h[(size_t)n*128 + dh + 64] = cB[tt];
    }
  }
}

template<typename ET>
__global__ __launch_bounds__(256) void edge_enc_kernel(
    const float* __restrict__ pos, const float* __restrict__ c_in,
    const int* __restrict__ snd, const int* __restrict__ rcv,
    const int* __restrict__ bnd, const float* __restrict__ emb_bond,
    const float* __restrict__ w1, const float* __restrict__ b1,
    const float* __restrict__ w2, const float* __restrict__ b2,
    ET* __restrict__ e, float* __restrict__ cutb, int E)
{
  __shared__ __align__(16) float xs[88*STRIDE];
  __shared__ __align__(16) float hs[256*STRIDE];
  __shared__ float grbf[TILE][8];
  __shared__ float gylm[TILE][9];
  __shared__ float gcut[TILE];
  __shared__ int   gbond[TILE];
  const int tid = threadIdx.x;
  const int e0 = blockIdx.x * TILE;
  if (tid < TILE) {
    const int ed = min(e0 + tid, E - 1);
    const int sa = snd[ed], ra = rcv[ed];
    const float ci = c_in[0];
    const float vx = (pos[sa*3+0] - pos[ra*3+0]) / ci;
    const float vy = (pos[sa*3+1] - pos[ra*3+1]) / ci;
    const float vz = (pos[sa*3+2] - pos[ra*3+2]) / ci;
    const float r  = sqrtf(vx*vx + vy*vy + vz*vz + 1e-12f);
    const float ir = 1.0f / r;
    const float ux = vx*ir, uy = vy*ir, uz = vz*ir;
    const float PI = 3.14159265358979323846f;
    const float pr = PI * r * 0.2f;
    const float c0 = 0.632455532033675866f;
    #pragma unroll
    for (int n = 0; n < 8; ++n)
      grbf[tid][n] = c0 * sinf((float)(n + 1) * pr) * ir;
    const float cv = 0.5f * (cosf(PI * fminf(r, 5.0f) * 0.2f) + 1.0f)
                   * (r < 5.0f ? 1.0f : 0.0f);
    gcut[tid] = cv;
    cutb[ed] = cv;
    const float s3  = 1.7320508075688772f;
    const float s5  = 2.2360679774997896f;
    const float s15 = 3.8729833462074170f;
    gylm[tid][0] = 1.0f;
    gylm[tid][1] = s3*ux; gylm[tid][2] = s3*uy; gylm[tid][3] = s3*uz;
    gylm[tid][4] = s15*ux*uy; gylm[tid][5] = s15*uy*uz;
    gylm[tid][6] = 0.5f*s5*(3.0f*uz*uz - 1.0f);
    gylm[tid][7] = s15*ux*uz;
    gylm[tid][8] = 0.5f*s15*(ux*ux - uy*uy);
    gbond[tid] = bnd[ed];
  }
  __syncthreads();
  for (int i = tid; i < TILE*88; i += 256) {
    const int t = i & 15, k = i >> 4;
    float v;
    if (k < 72) {
      const int n = k / 9, m = k - 9*n;
      v = grbf[t][n] * gylm[t][m] * gcut[t];
    } else {
      v = emb_bond[gbond[t]*16 + (k - 72)];
    }
    xs[k*STRIDE + t] = v;
  }
  __syncthreads();
  layer1_silu<88>(xs, w1, b1, hs, tid);
  __syncthreads();
  float cA[4], cB[4];
  layer2_bias(hs, w2, b2, tid, cA, cB);
  rms4(cA, cB);
  const int dh = tid & 63, tq = tid >> 6;
  #pragma unroll
  for (int tt = 0; tt < 4; ++tt) {
    const int ed = e0 + 4*tq + tt;
    if (ed < E) {
      storeE(&e[(size_t)ed*128 + dh],      cA[tt]);
      storeE(&e[(size_t)ed*128 + dh + 64], cB[tt]);
    }
  }
}

template<typename ET>
__global__ __launch_bounds__(256) void msg_kernel(
    const float* __restrict__ h, ET* __restrict__ e,
    float* __restrict__ agg, const float* __restrict__ cutb,
    const int* __restrict__ snd, const int* __restrict__ rcv,
    const float* __restrict__ w1, const float* __restrict__ b1,
    const float* __restrict__ w2, const float* __restrict__ b2,
    const float* __restrict__ gw, const float* __restrict__ gb,
    int E)
{
  __shared__ __align__(16) float xs[384*STRIDE];
  __shared__ __align__(16) float hs[256*STRIDE];
  __shared__ int   snd_s[TILE], rcv_s[TILE];
  __shared__ float cut_s[TILE];
  const int tid = threadIdx.x;
  const int e0 = blockIdx.x * TILE;
  if (tid < TILE) {
    const int ed = min(e0 + tid, E - 1);
    snd_s[tid] = snd[ed]; rcv_s[tid] = rcv[ed]; cut_s[tid] = cutb[ed];
  }
  __syncthreads();
  for (int i = tid; i < TILE*384; i += 256) {
    const int t = i / 384, k = i - t*384;
    float v;
    if (k < 128)      v = h[(size_t)snd_s[t]*128 + k];
    else if (k < 256) v = h[(size_t)rcv_s[t]*128 + (k - 128)];
    else {
      const int ed = min(e0 + t, E - 1);
      v = loadE(&e[(size_t)ed*128 + (k - 256)]);
    }
    xs[k*STRIDE + t] = v;
  }
  __syncthreads();
  layer1_silu<384>(xs, w1, b1, hs, tid);
  __syncthreads();
  float cA[4], cB[4];
  layer2_bias(hs, w2, b2, tid, cA, cB);
  rms4(cA, cB);
  const int dh = tid & 63, tq = tid >> 6;
  const float gwa = gw[dh], gwb = gw[dh + 64];
  const float gbv = gb[0];
  float gv[4];
  #pragma unroll
  for (int tt = 0; tt < 4; ++tt) gv[tt] = cA[tt]*gwa + cB[tt]*gwb;
  #pragma unroll
  for (int off = 32; off; off >>= 1) {
    #pragma unroll
    for (int tt = 0; tt < 4; ++tt) gv[tt] += __shfl_xor(gv[tt], off);
  }
  #pragma unroll
  for (int tt = 0; tt < 4; ++tt) {
    const int t = 4*tq + tt;
    const int ed = e0 + t;
    if (ed < E) {
      const float g = cut_s[t] / (1.0f + expf(-(gv[tt] + gbv)));
      const float eoA = xs[(256 + dh)*STRIDE + t];
      const float eoB = xs[(256 + dh + 64)*STRIDE + t];
      storeE(&e[(size_t)ed*128 + dh],      eoA + cA[tt]);
      storeE(&e[(size_t)ed*128 + dh + 64], eoB + cB[tt]);
      const int rv = rcv_s[t];
      atomicAdd(&agg[(size_t)rv*128 + dh],      cA[tt]*g);
      atomicAdd(&agg[(size_t)rv*128 + dh + 64], cB[tt]*g);
    }
  }
}

__global__ __launch_bounds__(256) void upd_kernel(
    float* __restrict__ h, const float* __restrict__ agg,
    const float* __restrict__ w1, const float* __restrict__ b1,
    const float* __restrict__ w2, const float* __restrict__ b2,
    int N)
{
  __shared__ __align__(16) float xs[256*STRIDE];
  __shared__ __align__(16) float hs[256*STRIDE];
  const int tid = threadIdx.x;
  const int n0 = blockIdx.x * TILE;
  for (int i = tid; i < TILE*256; i += 256) {
    const int t = i >> 8, k = i & 255;
    const int n = min(n0 + t, N - 1);
    const float v = (k < 128) ? h[(size_t)n*128 + k]
                              : agg[(size_t)n*128 + (k - 128)];
    xs[k*STRIDE + t] = v;
  }
  __syncthreads();
  layer1_silu<256>(xs, w1, b1, hs, tid);
  __syncthreads();
  float cA[4], cB[4];
  layer2_bias(hs, w2, b2, tid, cA, cB);
  rms4(cA, cB);
  const int dh = tid & 63, tq = tid >> 6;
  #pragma unroll
  for (int tt = 0; tt < 4; ++tt) {
    const int t = 4*tq + tt;
    const int n = n0 + t;
    if (n < N) {
      h[(size_t)n*128 + dh]      = xs[dh*STRIDE + t] + cA[tt];
      h[(size_t)n*128 + dh + 64] = xs[(dh + 64)*STRIDE + t] + cB[tt];
    }
  }
}

__global__ __launch_bounds__(256) void head_kernel(
    const float* __restrict__ h,
    const float* __restrict__ w1, const float* __restrict__ b1,
    const float* __restrict__ w2, const float* __restrict__ b2,
    float* __restrict__ out, int N)
{
  __shared__ __align__(16) float xs[128*STRIDE];
  __shared__ __align__(16) float hs[256*STRIDE];
  const int tid = threadIdx.x;
  const int n0 = blockIdx.x * TILE;
  for (int i = tid; i < TILE*128; i += 256) {
    const int t = i >> 7, k = i & 127;
    const int n = min(n0 + t, N - 1);
    xs[k*STRIDE + t] = h[(size_t)n*128 + k];
  }
  __syncthreads();
  layer1_silu<128>(xs, w1, b1, hs, tid);
  __syncthreads();
  if (tid < 48) {
    const int t = tid / 3, o = tid - 3*(tid/3);
    float acc = b2[o];
    for (int k = 0; k < 256; ++k)
      acc = fmaf(hs[k*STRIDE + t], w2[k*3 + o], acc);
    const int n = n0 + t;
    if (n < N) out[(size_t)n*3 + o] = acc;
  }
}

// ===========================================================================
extern "C" void kernel_launch(void* const* d_in, const int* in_sizes, int n_in,
                              void* d_out, int out_size, void* d_ws, size_t ws_size,
                              hipStream_t stream)
{
  const float* pos      = (const float*)d_in[0];
  const float* c_in     = (const float*)d_in[1];
  const int*   ati      = (const int*)d_in[2];
  const int*   aci      = (const int*)d_in[3];
  const int*   rci      = (const int*)d_in[4];
  const int*   rsi      = (const int*)d_in[5];
  const int*   snd      = (const int*)d_in[6];
  const int*   rcv      = (const int*)d_in[7];
  const int*   bnd      = (const int*)d_in[8];
  const float* emb_at   = (const float*)d_in[9];
  const float* emb_ac   = (const float*)d_in[10];
  const float* emb_rc   = (const float*)d_in[11];
  const float* emb_ri   = (const float*)d_in[12];
  const float* emb_bond = (const float*)d_in[13];
  const float* nenc_w1  = (const float*)d_in[14];
  const float* nenc_b1  = (const float*)d_in[15];
  const float* nenc_w2  = (const float*)d_in[16];
  const float* nenc_b2  = (const float*)d_in[17];
  const float* eenc_w1  = (const float*)d_in[18];
  const float* eenc_b1  = (const float*)d_in[19];
  const float* eenc_w2  = (const float*)d_in[20];
  const float* eenc_b2  = (const float*)d_in[21];
  const float* msg_w1   = (const float*)d_in[22];
  const float* msg_b1   = (const float*)d_in[23];
  const float* msg_w2   = (const float*)d_in[24];
  const float* msg_b2   = (const float*)d_in[25];
  const float* gate_w   = (const float*)d_in[26];
  const float* gate_b   = (const float*)d_in[27];
  const float* upd_w1   = (const float*)d_in[28];
  const float* upd_b1   = (const float*)d_in[29];
  const float* upd_w2   = (const float*)d_in[30];
  const float* upd_b2   = (const float*)d_in[31];
  const float* head_w1  = (const float*)d_in[32];
  const float* head_b1  = (const float*)d_in[33];
  const float* head_w2  = (const float*)d_in[34];
  const float* head_b2  = (const float*)d_in[35];

  const int N = in_sizes[0] / 3;
  const int E = in_sizes[6];

  // ---- workspace layout (MFMA path) ----
  char* ws = (char*)d_ws;
  float* hbuf   = (float*)ws;                   ws += (size_t)N * 128 * sizeof(float);
  float* aggbuf = (float*)ws;                   ws += (size_t)N * 128 * sizeof(float);
  float* cutbuf = (float*)ws;                   ws += (size_t)E * sizeof(float);
  unsigned short* packs = (unsigned short*)ws;
  // pack offsets (ushort units)
  const size_t eenc_w1p_o = 0;
  const size_t eenc_w2p_o = eenc_w1p_o + 16*4*512;
  const size_t msg_w1p_o  = eenc_w2p_o + 8*8*512;     // + s*98304
  const size_t msg_w2p_o  = msg_w1p_o + 4*(size_t)(16*12*512);
  const size_t upd_w1p_o  = msg_w2p_o + 4*(size_t)(8*8*512);
  const size_t upd_w2p_o  = upd_w1p_o + 4*(size_t)(16*8*512);
  const size_t packs_end  = upd_w2p_o + 4*(size_t)(8*8*512);
  ws += packs_end * sizeof(unsigned short);
  unsigned short* ebuf_mfma = (unsigned short*)ws;
  const size_t need_mfma = (size_t)(ws - (char*)d_ws) + (size_t)E * 128 * sizeof(unsigned short);

  const int nb_n16 = (N + TILE - 1) / TILE;
  const int n4     = N * 128 / 4;

  if (ws_size >= need_mfma) {
    // ---------------- MFMA path ----------------
    const int nb_e32 = (E + 31) / 32;
    const int nb_n32 = (N + 31) / 32;

    // weight packing (all tiny; every call, graph-safe)
    pack_w_kernel<<<96, 256, 0, stream>>>(eenc_w1, packs + eenc_w1p_o, 88, 4, 16);
    pack_w_kernel<<<96, 256, 0, stream>>>(eenc_w2, packs + eenc_w2p_o, 256, 8, 8);
    for (int s = 0; s < 4; ++s) {
      pack_w_kernel<<<96, 256, 0, stream>>>(msg_w1 + (size_t)s*384*256,
          packs + msg_w1p_o + (size_t)s*16*12*512, 384, 12, 16);
      pack_w_kernel<<<96, 256, 0, stream>>>(msg_w2 + (size_t)s*256*128,
          packs + msg_w2p_o + (size_t)s*8*8*512, 256, 8, 8);
      pack_w_kernel<<<96, 256, 0, stream>>>(upd_w1 + (size_t)s*256*256,
          packs + upd_w1p_o + (size_t)s*16*8*512, 256, 8, 16);
      pack_w_kernel<<<96, 256, 0, stream>>>(upd_w2 + (size_t)s*256*128,
          packs + upd_w2p_o + (size_t)s*8*8*512, 256, 8, 8);
    }

    node_enc_kernel<<<nb_n16, 256, 0, stream>>>(
        ati, aci, rci, rsi, emb_at, emb_ac, emb_rc, emb_ri,
        nenc_w1, nenc_b1, nenc_w2, nenc_b2, hbuf, N);

    edge_enc_mfma<<<nb_e32, 256, 0, stream>>>(
        pos, c_in, snd, rcv, bnd, emb_bond,
        packs + eenc_w1p_o, eenc_b1, packs + eenc_w2p_o, eenc_b2,
        ebuf_mfma, cutbuf, E);

    for (int s = 0; s < 4; ++s) {
      zero_kernel<<<(n4 + 255) / 256, 256, 0, stream>>>((float4*)aggbuf, n4);
      msg_mfma<<<nb_e32, 256, 0, stream>>>(
          hbuf, ebuf_mfma, aggbuf, cutbuf, snd, rcv,
          packs + msg_w1p_o + (size_t)s*16*12*512, msg_b1 + (size_t)s*256,
          packs + msg_w2p_o + (size_t)s*8*8*512,   msg_b2 + (size_t)s*128,
          gate_w + (size_t)s*128, gate_b + s, E);
      upd_mfma<<<nb_n32, 256, 0, stream>>>(
          hbuf, aggbuf,
          packs + upd_w1p_o + (size_t)s*16*8*512, upd_b1 + (size_t)s*256,
          packs + upd_w2p_o + (size_t)s*8*8*512,  upd_b2 + (size_t)s*128, N);
    }

    head_kernel<<<nb_n16, 256, 0, stream>>>(
        hbuf, head_w1, head_b1, head_w2, head_b2, (float*)d_out, N);
  } else {
    // ---------------- fallback: round-2 pipeline (bf16 e) ----------------
    __hip_bfloat16* ebuf = (__hip_bfloat16*)((char*)d_ws
        + (size_t)N*128*4 + (size_t)N*128*4 + (size_t)E*4);
    const int nb_e16 = (E + TILE - 1) / TILE;

    node_enc_kernel<<<nb_n16, 256, 0, stream>>>(
        ati, aci, rci, rsi, emb_at, emb_ac, emb_rc, emb_ri,
        nenc_w1, nenc_b1, nenc_w2, nenc_b2, hbuf, N);

    edge_enc_kernel<__hip_bfloat16><<<nb_e16, 256, 0, stream>>>(
        pos, c_in, snd, rcv, bnd, emb_bond,
        eenc_w1, eenc_b1, eenc_w2, eenc_b2, ebuf, cutbuf, E);

    for (int s = 0; s < 4; ++s) {
      zero_kernel<<<(n4 + 255) / 256, 256, 0, stream>>>((float4*)aggbuf, n4);
      msg_kernel<__hip_bfloat16><<<nb_e16, 256, 0, stream>>>(
          hbuf, ebuf, aggbuf, cutbuf, snd, rcv,
          msg_w1 + (size_t)s * 384 * 256, msg_b1 + (size_t)s * 256,
          msg_w2 + (size_t)s * 256 * 128, msg_b2 + (size_t)s * 128,
          gate_w + (size_t)s * 128, gate_b + s, E);
      upd_kernel<<<nb_n16, 256, 0, stream>>>(
          hbuf, aggbuf,
          upd_w1 + (size_t)s * 256 * 256, upd_b1 + (size_t)s * 256,
          upd_w2 + (size_t)s * 256 * 128, upd_b2 + (size_t)s * 128, N);
    }

    head_kernel<<<nb_n16, 256, 0, stream>>>(
        hbuf, head_w1, head_b1, head_w2, head_b2, (float*)d_out, N);
  }
}

// Round 4
// 2462.955 us; speedup vs baseline: 5.1429x; 1.1090x over previous
//
#include <hip/hip_runtime.h>
#include <hip/hip_bf16.h>
#include <math.h>

// ---------------------------------------------------------------------------
// MoleculeGNS — MFMA bf16 pipeline v2.
//   - bf16 h-mirror (hb): msg staging is pure short8 copies (no f2b VALU).
//   - x1/hsm LDS aliasing (compute->barrier->store split): msg LDS 41->25KB,
//     occupancy 3->6 blocks/CU.
//   - __expf-based silu/sigmoid.
// Fallback to fp32-VALU pipeline if ws_size too small.
// ---------------------------------------------------------------------------

#define TILE   16
#define STRIDE 20

using short8 = __attribute__((ext_vector_type(8))) short;
using f32x4  = __attribute__((ext_vector_type(4))) float;

__device__ __forceinline__ float silu_f(float x) {
  return x / (1.0f + __expf(-x));
}
__device__ __forceinline__ unsigned short f2b(float x) {
  union { float f; unsigned u; } v; v.f = x;
  unsigned r = v.u + 0x7fffu + ((v.u >> 16) & 1u);
  return (unsigned short)(r >> 16);
}
__device__ __forceinline__ float b2f(unsigned short h) {
  union { unsigned u; float f; } v; v.u = ((unsigned)h) << 16;
  return v.f;
}

// ---------------------------------------------------------------------------
// Weight pack: src row-major [Kreal][N=NF*16] fp32 -> frag-major bf16.
// dst[((nf*KS+kk)*64+l)*8+j] = src[kk*32+(l>>4)*8+j][nf*16+(l&15)], 0 pad.
// ---------------------------------------------------------------------------
__global__ __launch_bounds__(256) void pack_w_kernel(
    const float* __restrict__ src, unsigned short* __restrict__ dst,
    int Kreal, int KS, int NF)
{
  const int N = NF * 16;
  const int total = NF * KS * 512;
  for (int idx = blockIdx.x * 256 + threadIdx.x; idx < total; idx += gridDim.x * 256) {
    const int nf  = idx / (KS * 512);
    const int rem = idx - nf * (KS * 512);
    const int kk  = rem >> 9;
    const int p   = rem & 511;
    const int l   = p >> 3, j = p & 7;
    const int c   = nf * 16 + (l & 15);
    const int k   = kk * 32 + ((l >> 4) << 3) + j;
    dst[idx] = (k < Kreal) ? f2b(src[(size_t)k * N + c]) : (unsigned short)0;
  }
}

// ---------------------------------------------------------------------------
// Layer-1 compute: X1[32][KS1*32] (swizzled bf16 LDS) @ w1p -> acc[8] (regs).
// ---------------------------------------------------------------------------
template<int KS1>
__device__ __forceinline__ void mfma_l1_compute(const unsigned short* __restrict__ x1,
                                                const unsigned short* __restrict__ w1p,
                                                int tid, f32x4 acc[8])
{
  const int w  = tid >> 6;
  const int l  = tid & 63;
  const int lr = l & 15;
  const int lk = (l >> 4) << 3;
  const int RS = KS1 * 32;
  const f32x4 zz = {0.f, 0.f, 0.f, 0.f};
  #pragma unroll
  for (int i = 0; i < 8; ++i) acc[i] = zz;

  for (int kk = 0; kk < KS1; ++kk) {
    short8 af[2];
    #pragma unroll
    for (int mf = 0; mf < 2; ++mf) {
      const int r = mf * 16 + lr;
      const int k = kk * 32 + lk;
      af[mf] = *(const short8*)&x1[r * RS + ((((k >> 3) ^ (r & 7))) << 3)];
    }
    #pragma unroll
    for (int nf = 0; nf < 4; ++nf) {
      const int nfg = w * 4 + nf;
      const short8 bf = *(const short8*)&w1p[(size_t)(((nfg * KS1) + kk) * 64 + l) * 8];
      #pragma unroll
      for (int mf = 0; mf < 2; ++mf)
        acc[mf * 4 + nf] = __builtin_amdgcn_mfma_f32_16x16x32_bf16(af[mf], bf, acc[mf * 4 + nf], 0, 0, 0);
    }
  }
}

// Layer-1 store: bias + silu + bf16 -> hsm[32][256] swizzled (may alias x1;
// caller must barrier between compute and store).
__device__ __forceinline__ void l1_store_silu(const f32x4 acc[8],
                                              const float* __restrict__ b1,
                                              unsigned short* __restrict__ hsm,
                                              int tid)
{
  const int w = tid >> 6, l = tid & 63, lr = l & 15;
  #pragma unroll
  for (int nf = 0; nf < 4; ++nf) {
    const int c = (w * 4 + nf) * 16 + lr;
    const float bias = b1[c];
    #pragma unroll
    for (int mf = 0; mf < 2; ++mf) {
      #pragma unroll
      for (int q = 0; q < 4; ++q) {
        const int r = mf * 16 + ((l >> 4) << 2) + q;
        const float v = silu_f(acc[mf * 4 + nf][q] + bias);
        hsm[r * 256 + (((c >> 3) ^ (r & 7)) << 3) + (c & 7)] = f2b(v);
      }
    }
  }
}

// ---------------------------------------------------------------------------
// Layer 2: hsm[32][256] @ w2p [256,128] + b2 -> acc2[4] (wave cols 32w..).
// ---------------------------------------------------------------------------
__device__ __forceinline__ void mfma_l2(const unsigned short* __restrict__ hsm,
                                        const unsigned short* __restrict__ w2p,
                                        const float* __restrict__ b2,
                                        int tid, f32x4 acc2[4])
{
  const int w  = tid >> 6;
  const int l  = tid & 63;
  const int lr = l & 15;
  const int lk = (l >> 4) << 3;
  const f32x4 zz = {0.f, 0.f, 0.f, 0.f};
  #pragma unroll
  for (int i = 0; i < 4; ++i) acc2[i] = zz;

  for (int kk = 0; kk < 8; ++kk) {
    short8 af[2];
    #pragma unroll
    for (int mf = 0; mf < 2; ++mf) {
      const int r = mf * 16 + lr;
      const int k = kk * 32 + lk;
      af[mf] = *(const short8*)&hsm[r * 256 + (((k >> 3) ^ (r & 7)) << 3)];
    }
    #pragma unroll
    for (int nf2 = 0; nf2 < 2; ++nf2) {
      const int nfg = w * 2 + nf2;
      const short8 bf = *(const short8*)&w2p[(size_t)(((nfg * 8) + kk) * 64 + l) * 8];
      #pragma unroll
      for (int mf = 0; mf < 2; ++mf)
        acc2[mf * 2 + nf2] = __builtin_amdgcn_mfma_f32_16x16x32_bf16(af[mf], bf, acc2[mf * 2 + nf2], 0, 0, 0);
    }
  }
  #pragma unroll
  for (int nf2 = 0; nf2 < 2; ++nf2) {
    const float bias = b2[(w * 2 + nf2) * 16 + lr];
    #pragma unroll
    for (int mf = 0; mf < 2; ++mf) {
      #pragma unroll
      for (int q = 0; q < 4; ++q) acc2[mf * 2 + nf2][q] += bias;
    }
  }
}

// ---------------------------------------------------------------------------
// RMS over d=128 for 32 rows; rsum pre-zeroed; internal barrier.
// ---------------------------------------------------------------------------
__device__ __forceinline__ void rms_reduce(const f32x4 acc2[4], float* rsum,
                                           int tid, float mval[2][2][4])
{
  const int l = tid & 63;
  #pragma unroll
  for (int mf = 0; mf < 2; ++mf) {
    #pragma unroll
    for (int q = 0; q < 4; ++q) {
      float s = acc2[mf * 2][q] * acc2[mf * 2][q]
              + acc2[mf * 2 + 1][q] * acc2[mf * 2 + 1][q];
      s += __shfl_xor(s, 1); s += __shfl_xor(s, 2);
      s += __shfl_xor(s, 4); s += __shfl_xor(s, 8);
      if ((l & 15) == 0)
        atomicAdd(&rsum[mf * 16 + ((l >> 4) << 2) + q], s);
    }
  }
  __syncthreads();
  #pragma unroll
  for (int mf = 0; mf < 2; ++mf) {
    #pragma unroll
    for (int q = 0; q < 4; ++q) {
      const int r = mf * 16 + ((l >> 4) << 2) + q;
      const float inv = rsqrtf(rsum[r] * (1.0f / 128.0f) + 1e-6f);
      #pragma unroll
      for (int nf2 = 0; nf2 < 2; ++nf2)
        mval[mf][nf2][q] = acc2[mf * 2 + nf2][q] * inv;
    }
  }
}

// ---------------------------------------------------------------------------
// Edge encoder (MFMA): geometry -> X1[32][128] -> MLP -> RMS -> e (bf16), cut.
// ---------------------------------------------------------------------------
__global__ __launch_bounds__(256, 5) void edge_enc_mfma(
    const float* __restrict__ pos, const float* __restrict__ c_in,
    const int* __restrict__ snd, const int* __restrict__ rcv,
    const int* __restrict__ bnd, const float* __restrict__ embb,
    const unsigned short* __restrict__ w1p, const float* __restrict__ b1,
    const unsigned short* __restrict__ w2p, const float* __restrict__ b2,
    unsigned short* __restrict__ e_g, float* __restrict__ cutb, int E)
{
  __shared__ __align__(16) unsigned short smem[32 * 256];  // x1 (8KB) / hsm (16KB) aliased
  unsigned short* x1  = smem;
  unsigned short* hsm = smem;
  __shared__ float grbf[32][8];
  __shared__ float gylm[32][9];
  __shared__ float gcut[32];
  __shared__ int   gbond[32];
  __shared__ float rsum[32];
  const int tid = threadIdx.x;
  const int e0  = blockIdx.x * 32;

  if (tid < 32) {
    rsum[tid] = 0.f;
    const int ed = min(e0 + tid, E - 1);
    const int sa = snd[ed], ra = rcv[ed];
    const float ci = c_in[0];
    const float vx = (pos[sa * 3 + 0] - pos[ra * 3 + 0]) / ci;
    const float vy = (pos[sa * 3 + 1] - pos[ra * 3 + 1]) / ci;
    const float vz = (pos[sa * 3 + 2] - pos[ra * 3 + 2]) / ci;
    const float r  = sqrtf(vx * vx + vy * vy + vz * vz + 1e-12f);
    const float ir = 1.0f / r;
    const float ux = vx * ir, uy = vy * ir, uz = vz * ir;
    const float PI = 3.14159265358979323846f;
    const float pr = PI * r * 0.2f;
    const float c0 = 0.632455532033675866f;   // sqrt(2/5)
    #pragma unroll
    for (int n = 0; n < 8; ++n)
      grbf[tid][n] = c0 * sinf((float)(n + 1) * pr) * ir;
    const float cv = 0.5f * (cosf(PI * fminf(r, 5.0f) * 0.2f) + 1.0f)
                   * (r < 5.0f ? 1.0f : 0.0f);
    gcut[tid] = cv;
    if (e0 + tid < E) cutb[e0 + tid] = cv;
    const float s3  = 1.7320508075688772f;
    const float s5  = 2.2360679774997896f;
    const float s15 = 3.8729833462074170f;
    gylm[tid][0] = 1.0f;
    gylm[tid][1] = s3 * ux; gylm[tid][2] = s3 * uy; gylm[tid][3] = s3 * uz;
    gylm[tid][4] = s15 * ux * uy; gylm[tid][5] = s15 * uy * uz;
    gylm[tid][6] = 0.5f * s5 * (3.0f * uz * uz - 1.0f);
    gylm[tid][7] = s15 * ux * uz;
    gylm[tid][8] = 0.5f * s15 * (ux * ux - uy * uy);
    gbond[tid] = bnd[ed];
  }
  __syncthreads();
  for (int i = tid; i < 32 * 16; i += 256) {
    const int r = i >> 4, g = i & 15;
    union { short8 v; unsigned short u[8]; } t;
    #pragma unroll
    for (int j = 0; j < 8; ++j) {
      const int k = g * 8 + j;
      float v;
      if (k < 72) { const int n = k / 9, mm = k - 9 * n; v = grbf[r][n] * gylm[r][mm] * gcut[r]; }
      else if (k < 88) v = embb[gbond[r] * 16 + (k - 72)];
      else v = 0.f;
      t.u[j] = f2b(v);
    }
    *(short8*)&x1[r * 128 + ((g ^ (r & 7)) << 3)] = t.v;
  }
  __syncthreads();
  f32x4 acc1[8];
  mfma_l1_compute<4>(x1, w1p, tid, acc1);
  __syncthreads();                        // x1 dead; hsm aliases it
  l1_store_silu(acc1, b1, hsm, tid);
  __syncthreads();
  f32x4 acc2[4];
  mfma_l2(hsm, w2p, b2, tid, acc2);
  float mval[2][2][4];
  rms_reduce(acc2, rsum, tid, mval);
  const int l = tid & 63, w = tid >> 6, lr = l & 15;
  #pragma unroll
  for (int mf = 0; mf < 2; ++mf) {
    #pragma unroll
    for (int q = 0; q < 4; ++q) {
      const int r = mf * 16 + ((l >> 4) << 2) + q;
      const int ed = e0 + r;
      if (ed < E) {
        #pragma unroll
        for (int nf2 = 0; nf2 < 2; ++nf2) {
          const int c2 = (w * 2 + nf2) * 16 + lr;
          e_g[(size_t)ed * 128 + c2] = f2b(mval[mf][nf2][q]);
        }
      }
    }
  }
}

// ---------------------------------------------------------------------------
// Message step (MFMA): X1 = [hb_s | hb_r | e] (pure short8 copies) -> MLP
// -> RMS -> gate, e+=m (global RMW), agg atomics.
// ---------------------------------------------------------------------------
__global__ __launch_bounds__(256, 5) void msg_mfma(
    const unsigned short* __restrict__ hb, unsigned short* __restrict__ e_g,
    float* __restrict__ agg, const float* __restrict__ cutb,
    const int* __restrict__ snd, const int* __restrict__ rcv,
    const unsigned short* __restrict__ w1p, const float* __restrict__ b1,
    const unsigned short* __restrict__ w2p, const float* __restrict__ b2,
    const float* __restrict__ gw, const float* __restrict__ gb, int E)
{
  __shared__ __align__(16) unsigned short smem[32 * 384];  // x1 (24KB) / hsm (16KB) aliased
  unsigned short* x1  = smem;
  unsigned short* hsm = smem;
  __shared__ int   snd_s[32], rcv_s[32];
  __shared__ float cut_s[32];
  __shared__ float rsum[32], gsum[32];
  const int tid = threadIdx.x;
  const int e0  = blockIdx.x * 32;

  if (tid < 32) {
    rsum[tid] = 0.f; gsum[tid] = 0.f;
    const int ed = min(e0 + tid, E - 1);
    snd_s[tid] = snd[ed]; rcv_s[tid] = rcv[ed]; cut_s[tid] = cutb[ed];
  }
  __syncthreads();
  for (int i = tid; i < 32 * 48; i += 256) {
    const int r = i / 48, g = i - r * 48;
    short8 t;
    if (g < 32) {
      const int node = (g < 16) ? snd_s[r] : rcv_s[r];
      t = *(const short8*)&hb[(size_t)node * 128 + (g & 15) * 8];
    } else {
      const int ed = min(e0 + r, E - 1);
      t = *(const short8*)&e_g[(size_t)ed * 128 + (g - 32) * 8];
    }
    *(short8*)&x1[r * 384 + ((g ^ (r & 7)) << 3)] = t;
  }
  __syncthreads();
  f32x4 acc1[8];
  mfma_l1_compute<12>(x1, w1p, tid, acc1);
  __syncthreads();                        // x1 dead; hsm aliases it
  l1_store_silu(acc1, b1, hsm, tid);
  __syncthreads();
  f32x4 acc2[4];
  mfma_l2(hsm, w2p, b2, tid, acc2);
  float mval[2][2][4];
  rms_reduce(acc2, rsum, tid, mval);

  const int l = tid & 63, w = tid >> 6, lr = l & 15;
  const float gw0 = gw[(w * 2 + 0) * 16 + lr];
  const float gw1 = gw[(w * 2 + 1) * 16 + lr];
  #pragma unroll
  for (int mf = 0; mf < 2; ++mf) {
    #pragma unroll
    for (int q = 0; q < 4; ++q) {
      float p = mval[mf][0][q] * gw0 + mval[mf][1][q] * gw1;
      p += __shfl_xor(p, 1); p += __shfl_xor(p, 2);
      p += __shfl_xor(p, 4); p += __shfl_xor(p, 8);
      if ((l & 15) == 0)
        atomicAdd(&gsum[mf * 16 + ((l >> 4) << 2) + q], p);
    }
  }
  __syncthreads();
  const float gbv = gb[0];
  #pragma unroll
  for (int mf = 0; mf < 2; ++mf) {
    #pragma unroll
    for (int q = 0; q < 4; ++q) {
      const int r = mf * 16 + ((l >> 4) << 2) + q;
      const int ed = e0 + r;
      if (ed < E) {
        const float gr = cut_s[r] / (1.0f + __expf(-(gsum[r] + gbv)));
        const int rv = rcv_s[r];
        #pragma unroll
        for (int nf2 = 0; nf2 < 2; ++nf2) {
          const int c2 = (w * 2 + nf2) * 16 + lr;
          const float m = mval[mf][nf2][q];
          const float eo = b2f(e_g[(size_t)ed * 128 + c2]);   // old e (not yet overwritten)
          e_g[(size_t)ed * 128 + c2] = f2b(eo + m);
          atomicAdd(&agg[(size_t)rv * 128 + c2], m * gr);
        }
      }
    }
  }
}

// ---------------------------------------------------------------------------
// Update step (MFMA): X1 = [hb | agg] -> MLP -> RMS -> h += m; hb mirror.
// ---------------------------------------------------------------------------
__global__ __launch_bounds__(256, 5) void upd_mfma(
    float* __restrict__ h, unsigned short* __restrict__ hb,
    const float* __restrict__ agg,
    const unsigned short* __restrict__ w1p, const float* __restrict__ b1,
    const unsigned short* __restrict__ w2p, const float* __restrict__ b2,
    int N)
{
  __shared__ __align__(16) unsigned short smem[32 * 256];  // x1 (16KB) / hsm (16KB) aliased
  unsigned short* x1  = smem;
  unsigned short* hsm = smem;
  __shared__ float rsum[32];
  const int tid = threadIdx.x;
  const int n0  = blockIdx.x * 32;
  if (tid < 32) rsum[tid] = 0.f;
  __syncthreads();
  for (int i = tid; i < 32 * 32; i += 256) {
    const int r = i >> 5, g = i & 31;
    const int n = min(n0 + r, N - 1);
    short8 t;
    if (g < 16) {
      t = *(const short8*)&hb[(size_t)n * 128 + g * 8];
    } else {
      const float4 f0 = *(const float4*)&agg[(size_t)n * 128 + (g - 16) * 8];
      const float4 f1 = *(const float4*)&agg[(size_t)n * 128 + (g - 16) * 8 + 4];
      union { short8 v; unsigned short u[8]; } tt;
      tt.u[0] = f2b(f0.x); tt.u[1] = f2b(f0.y); tt.u[2] = f2b(f0.z); tt.u[3] = f2b(f0.w);
      tt.u[4] = f2b(f1.x); tt.u[5] = f2b(f1.y); tt.u[6] = f2b(f1.z); tt.u[7] = f2b(f1.w);
      t = tt.v;
    }
    *(short8*)&x1[r * 256 + ((g ^ (r & 7)) << 3)] = t;
  }
  __syncthreads();
  f32x4 acc1[8];
  mfma_l1_compute<8>(x1, w1p, tid, acc1);
  __syncthreads();
  l1_store_silu(acc1, b1, hsm, tid);
  __syncthreads();
  f32x4 acc2[4];
  mfma_l2(hsm, w2p, b2, tid, acc2);
  float mval[2][2][4];
  rms_reduce(acc2, rsum, tid, mval);
  const int l = tid & 63, w = tid >> 6, lr = l & 15;
  #pragma unroll
  for (int mf = 0; mf < 2; ++mf) {
    #pragma unroll
    for (int q = 0; q < 4; ++q) {
      const int r = mf * 16 + ((l >> 4) << 2) + q;
      const int n = n0 + r;
      if (n < N) {
        #pragma unroll
        for (int nf2 = 0; nf2 < 2; ++nf2) {
          const int c2 = (w * 2 + nf2) * 16 + lr;
          const float nh = h[(size_t)n * 128 + c2] + mval[mf][nf2][q];
          h[(size_t)n * 128 + c2]  = nh;
          hb[(size_t)n * 128 + c2] = f2b(nh);
        }
      }
    }
  }
}

// ===========================================================================
// fp32 pipeline (node/head kernels + full fallback).
// ===========================================================================

__device__ __forceinline__ float loadE(const float* p)          { return *p; }
__device__ __forceinline__ float loadE(const __hip_bfloat16* p) { return __bfloat162float(*p); }
__device__ __forceinline__ void  storeE(float* p, float v)          { *p = v; }
__device__ __forceinline__ void  storeE(__hip_bfloat16* p, float v) { *p = __float2bfloat16(v); }

template<int K1>
__device__ __forceinline__ void layer1_silu(const float* __restrict__ xs,
                                            const float* __restrict__ w1,
                                            const float* __restrict__ b1,
                                            float* __restrict__ hs, int tid)
{
  const int jh = tid & 127;
  const int tp = tid >> 7;
  const int tbase = 8 * tp;
  float a[8] = {0,0,0,0,0,0,0,0};
  float b[8] = {0,0,0,0,0,0,0,0};
  const float* wp = w1 + jh;
  for (int k = 0; k < K1; ++k) {
    const float4 x0 = *(const float4*)&xs[k*STRIDE + tbase];
    const float4 x1 = *(const float4*)&xs[k*STRIDE + tbase + 4];
    const float wa = wp[k*256];
    const float wb = wp[k*256 + 128];
    a[0] = fmaf(x0.x, wa, a[0]); a[1] = fmaf(x0.y, wa, a[1]);
    a[2] = fmaf(x0.z, wa, a[2]); a[3] = fmaf(x0.w, wa, a[3]);
    a[4] = fmaf(x1.x, wa, a[4]); a[5] = fmaf(x1.y, wa, a[5]);
    a[6] = fmaf(x1.z, wa, a[6]); a[7] = fmaf(x1.w, wa, a[7]);
    b[0] = fmaf(x0.x, wb, b[0]); b[1] = fmaf(x0.y, wb, b[1]);
    b[2] = fmaf(x0.z, wb, b[2]); b[3] = fmaf(x0.w, wb, b[3]);
    b[4] = fmaf(x1.x, wb, b[4]); b[5] = fmaf(x1.y, wb, b[5]);
    b[6] = fmaf(x1.z, wb, b[6]); b[7] = fmaf(x1.w, wb, b[7]);
  }
  const float ba = b1[jh];
  const float bb = b1[jh + 128];
  float4 oa0, oa1, ob0, ob1;
  oa0.x = silu_f(a[0] + ba); oa0.y = silu_f(a[1] + ba);
  oa0.z = silu_f(a[2] + ba); oa0.w = silu_f(a[3] + ba);
  oa1.x = silu_f(a[4] + ba); oa1.y = silu_f(a[5] + ba);
  oa1.z = silu_f(a[6] + ba); oa1.w = silu_f(a[7] + ba);
  ob0.x = silu_f(b[0] + bb); ob0.y = silu_f(b[1] + bb);
  ob0.z = silu_f(b[2] + bb); ob0.w = silu_f(b[3] + bb);
  ob1.x = silu_f(b[4] + bb); ob1.y = silu_f(b[5] + bb);
  ob1.z = silu_f(b[6] + bb); ob1.w = silu_f(b[7] + bb);
  *(float4*)&hs[jh*STRIDE + tbase]           = oa0;
  *(float4*)&hs[jh*STRIDE + tbase + 4]       = oa1;
  *(float4*)&hs[(jh+128)*STRIDE + tbase]     = ob0;
  *(float4*)&hs[(jh+128)*STRIDE + tbase + 4] = ob1;
}

__device__ __forceinline__ void layer2_bias(const float* __restrict__ hs,
                                            const float* __restrict__ w2,
                                            const float* __restrict__ b2,
                                            int tid, float cA[4], float cB[4])
{
  const int dh = tid & 63;
  const int tq = tid >> 6;
  const int tbase = 4 * tq;
  cA[0]=cA[1]=cA[2]=cA[3]=0.0f;
  cB[0]=cB[1]=cB[2]=cB[3]=0.0f;
  const float* wp = w2 + dh;
  for (int k = 0; k < 256; ++k) {
    const float4 hv = *(const float4*)&hs[k*STRIDE + tbase];
    const float wa = wp[k*128];
    const float wb = wp[k*128 + 64];
    cA[0] = fmaf(hv.x, wa, cA[0]); cA[1] = fmaf(hv.y, wa, cA[1]);
    cA[2] = fmaf(hv.z, wa, cA[2]); cA[3] = fmaf(hv.w, wa, cA[3]);
    cB[0] = fmaf(hv.x, wb, cB[0]); cB[1] = fmaf(hv.y, wb, cB[1]);
    cB[2] = fmaf(hv.z, wb, cB[2]); cB[3] = fmaf(hv.w, wb, cB[3]);
  }
  const float b2a = b2[dh];
  const float b2b = b2[dh + 64];
  #pragma unroll
  for (int tt = 0; tt < 4; ++tt) { cA[tt] += b2a; cB[tt] += b2b; }
}

__device__ __forceinline__ void rms4(float cA[4], float cB[4])
{
  float s[4];
  #pragma unroll
  for (int tt = 0; tt < 4; ++tt) s[tt] = cA[tt]*cA[tt] + cB[tt]*cB[tt];
  #pragma unroll
  for (int off = 32; off; off >>= 1) {
    #pragma unroll
    for (int tt = 0; tt < 4; ++tt) s[tt] += __shfl_xor(s[tt], off);
  }
  #pragma unroll
  for (int tt = 0; tt < 4; ++tt) {
    const float inv = rsqrtf(s[tt] * (1.0f/128.0f) + 1e-6f);
    cA[tt] *= inv; cB[tt] *= inv;
  }
}

__global__ __launch_bounds__(256) void zero_kernel(float4* __restrict__ p, int n4)
{
  const int i = blockIdx.x * 256 + threadIdx.x;
  if (i < n4) p[i] = make_float4(0.f, 0.f, 0.f, 0.f);
}

// Node encoder (fp32) + optional bf16 mirror.
__global__ __launch_bounds__(256) void node_enc_kernel(
    const int* __restrict__ ati, const int* __restrict__ aci,
    const int* __restrict__ rci, const int* __restrict__ rsi,
    const float* __restrict__ emb_at, const float* __restrict__ emb_ac,
    const float* __restrict__ emb_rc, const float* __restrict__ emb_ri,
    const float* __restrict__ w1, const float* __restrict__ b1,
    const float* __restrict__ w2, const float* __restrict__ b2,
    float* __restrict__ h, unsigned short* __restrict__ hb, int N)
{
  __shared__ __align__(16) float xs[128*STRIDE];
  __shared__ __align__(16) float hs[256*STRIDE];
  __shared__ int idx_s[4][TILE];
  const int tid = threadIdx.x;
  const int n0 = blockIdx.x * TILE;
  if (tid < TILE) {
    const int n = min(n0 + tid, N - 1);
    idx_s[0][tid] = ati[n]; idx_s[1][tid] = aci[n];
    idx_s[2][tid] = rci[n]; idx_s[3][tid] = rsi[n];
  }
  __syncthreads();
  for (int i = tid; i < TILE*128; i += 256) {
    const int t = i >> 7, k = i & 127;
    const int seg = k >> 5, kk = k & 31;
    const float* tab = (seg == 0) ? emb_at : (seg == 1) ? emb_ac
                     : (seg == 2) ? emb_rc : emb_ri;
    xs[k*STRIDE + t] = tab[idx_s[seg][t]*32 + kk];
  }
  __syncthreads();
  layer1_silu<128>(xs, w1, b1, hs, tid);
  __syncthreads();
  float cA[4], cB[4];
  layer2_bias(hs, w2, b2, tid, cA, cB);
  rms4(cA, cB);
  const int dh = tid & 63, tq = tid >> 6;
  #pragma unroll
  for (int tt = 0; tt < 4; ++tt) {
    const int n = n0 + 4*tq + tt;
    if (n < N) {
      h[(size_t)n*128 + dh]      = cA[tt];
      h[(size_t)n*128 + dh + 64] = cB[tt];
      if (hb) {
        hb[(size_t)n*128 + dh]      = f2b(cA[tt]);
        hb[(size_t)n*128 + dh + 64] = f2b(cB[tt]);
      }
    }
  }
}

template<typename ET>
__global__ __launch_bounds__(256) void edge_enc_kernel(
    const float* __restrict__ pos, const float* __restrict__ c_in,
    const int* __restrict__ snd, const int* __restrict__ rcv,
    const int* __restrict__ bnd, const float* __restrict__ emb_bond,
    const float* __restrict__ w1, const float* __restrict__ b1,
    const float* __restrict__ w2, const float* __restrict__ b2,
    ET* __restrict__ e, float* __restrict__ cutb, int E)
{
  __shared__ __align__(16) float xs[88*STRIDE];
  __shared__ __align__(16) float hs[256*STRIDE];
  __shared__ float grbf[TILE][8];
  __shared__ float gylm[TILE][9];
  __shared__ float gcut[TILE];
  __shared__ int   gbond[TILE];
  const int tid = threadIdx.x;
  const int e0 = blockIdx.x * TILE;
  if (tid < TILE) {
    const int ed = min(e0 + tid, E - 1);
    const int sa = snd[ed], ra = rcv[ed];
    const float ci = c_in[0];
    const float vx = (pos[sa*3+0] - pos[ra*3+0]) / ci;
    const float vy = (pos[sa*3+1] - pos[ra*3+1]) / ci;
    const float vz = (pos[sa*3+2] - pos[ra*3+2]) / ci;
    const float r  = sqrtf(vx*vx + vy*vy + vz*vz + 1e-12f);
    const float ir = 1.0f / r;
    const float ux = vx*ir, uy = vy*ir, uz = vz*ir;
    const float PI = 3.14159265358979323846f;
    const float pr = PI * r * 0.2f;
    const float c0 = 0.632455532033675866f;
    #pragma unroll
    for (int n = 0; n < 8; ++n)
      grbf[tid][n] = c0 * sinf((float)(n + 1) * pr) * ir;
    const float cv = 0.5f * (cosf(PI * fminf(r, 5.0f) * 0.2f) + 1.0f)
                   * (r < 5.0f ? 1.0f : 0.0f);
    gcut[tid] = cv;
    cutb[ed] = cv;
    const float s3  = 1.7320508075688772f;
    const float s5  = 2.2360679774997896f;
    const float s15 = 3.8729833462074170f;
    gylm[tid][0] = 1.0f;
    gylm[tid][1] = s3*ux; gylm[tid][2] = s3*uy; gylm[tid][3] = s3*uz;
    gylm[tid][4] = s15*ux*uy; gylm[tid][5] = s15*uy*uz;
    gylm[tid][6] = 0.5f*s5*(3.0f*uz*uz - 1.0f);
    gylm[tid][7] = s15*ux*uz;
    gylm[tid][8] = 0.5f*s15*(ux*ux - uy*uy);
    gbond[tid] = bnd[ed];
  }
  __syncthreads();
  for (int i = tid; i < TILE*88; i += 256) {
    const int t = i & 15, k = i >> 4;
    float v;
    if (k < 72) {
      const int n = k / 9, m = k - 9*n;
      v = grbf[t][n] * gylm[t][m] * gcut[t];
    } else {
      v = emb_bond[gbond[t]*16 + (k - 72)];
    }
    xs[k*STRIDE + t] = v;
  }
  __syncthreads();
  layer1_silu<88>(xs, w1, b1, hs, tid);
  __syncthreads();
  float cA[4], cB[4];
  layer2_bias(hs, w2, b2, tid, cA, cB);
  rms4(cA, cB);
  const int dh = tid & 63, tq = tid >> 6;
  #pragma unroll
  for (int tt = 0; tt < 4; ++tt) {
    const int ed = e0 + 4*tq + tt;
    if (ed < E) {
      storeE(&e[(size_t)ed*128 + dh],      cA[tt]);
      storeE(&e[(size_t)ed*128 + dh + 64], cB[tt]);
    }
  }
}

template<typename ET>
__global__ __launch_bounds__(256) void msg_kernel(
    const float* __restrict__ h, ET* __restrict__ e,
    float* __restrict__ agg, const float* __restrict__ cutb,
    const int* __restrict__ snd, const int* __restrict__ rcv,
    const float* __restrict__ w1, const float* __restrict__ b1,
    const float* __restrict__ w2, const float* __restrict__ b2,
    const float* __restrict__ gw, const float* __restrict__ gb,
    int E)
{
  __shared__ __align__(16) float xs[384*STRIDE];
  __shared__ __align__(16) float hs[256*STRIDE];
  __shared__ int   snd_s[TILE], rcv_s[TILE];
  __shared__ float cut_s[TILE];
  const int tid = threadIdx.x;
  const int e0 = blockIdx.x * TILE;
  if (tid < TILE) {
    const int ed = min(e0 + tid, E - 1);
    snd_s[tid] = snd[ed]; rcv_s[tid] = rcv[ed]; cut_s[tid] = cutb[ed];
  }
  __syncthreads();
  for (int i = tid; i < TILE*384; i += 256) {
    const int t = i / 384, k = i - t*384;
    float v;
    if (k < 128)      v = h[(size_t)snd_s[t]*128 + k];
    else if (k < 256) v = h[(size_t)rcv_s[t]*128 + (k - 128)];
    else {
      const int ed = min(e0 + t, E - 1);
      v = loadE(&e[(size_t)ed*128 + (k - 256)]);
    }
    xs[k*STRIDE + t] = v;
  }
  __syncthreads();
  layer1_silu<384>(xs, w1, b1, hs, tid);
  __syncthreads();
  float cA[4], cB[4];
  layer2_bias(hs, w2, b2, tid, cA, cB);
  rms4(cA, cB);
  const int dh = tid & 63, tq = tid >> 6;
  const float gwa = gw[dh], gwb = gw[dh + 64];
  const float gbv = gb[0];
  float gv[4];
  #pragma unroll
  for (int tt = 0; tt < 4; ++tt) gv[tt] = cA[tt]*gwa + cB[tt]*gwb;
  #pragma unroll
  for (int off = 32; off; off >>= 1) {
    #pragma unroll
    for (int tt = 0; tt < 4; ++tt) gv[tt] += __shfl_xor(gv[tt], off);
  }
  #pragma unroll
  for (int tt = 0; tt < 4; ++tt) {
    const int t = 4*tq + tt;
    const int ed = e0 + t;
    if (ed < E) {
      const float g = cut_s[t] / (1.0f + __expf(-(gv[tt] + gbv)));
      const float eoA = xs[(256 + dh)*STRIDE + t];
      const float eoB = xs[(256 + dh + 64)*STRIDE + t];
      storeE(&e[(size_t)ed*128 + dh],      eoA + cA[tt]);
      storeE(&e[(size_t)ed*128 + dh + 64], eoB + cB[tt]);
      const int rv = rcv_s[t];
      atomicAdd(&agg[(size_t)rv*128 + dh],      cA[tt]*g);
      atomicAdd(&agg[(size_t)rv*128 + dh + 64], cB[tt]*g);
    }
  }
}

__global__ __launch_bounds__(256) void upd_kernel(
    float* __restrict__ h, const float* __restrict__ agg,
    const float* __restrict__ w1, const float* __restrict__ b1,
    const float* __restrict__ w2, const float* __restrict__ b2,
    int N)
{
  __shared__ __align__(16) float xs[256*STRIDE];
  __shared__ __align__(16) float hs[256*STRIDE];
  const int tid = threadIdx.x;
  const int n0 = blockIdx.x * TILE;
  for (int i = tid; i < TILE*256; i += 256) {
    const int t = i >> 8, k = i & 255;
    const int n = min(n0 + t, N - 1);
    const float v = (k < 128) ? h[(size_t)n*128 + k]
                              : agg[(size_t)n*128 + (k - 128)];
    xs[k*STRIDE + t] = v;
  }
  __syncthreads();
  layer1_silu<256>(xs, w1, b1, hs, tid);
  __syncthreads();
  float cA[4], cB[4];
  layer2_bias(hs, w2, b2, tid, cA, cB);
  rms4(cA, cB);
  const int dh = tid & 63, tq = tid >> 6;
  #pragma unroll
  for (int tt = 0; tt < 4; ++tt) {
    const int t = 4*tq + tt;
    const int n = n0 + t;
    if (n < N) {
      h[(size_t)n*128 + dh]      = xs[dh*STRIDE + t] + cA[tt];
      h[(size_t)n*128 + dh + 64] = xs[(dh + 64)*STRIDE + t] + cB[tt];
    }
  }
}

__global__ __launch_bounds__(256) void head_kernel(
    const float* __restrict__ h,
    const float* __restrict__ w1, const float* __restrict__ b1,
    const float* __restrict__ w2, const float* __restrict__ b2,
    float* __restrict__ out, int N)
{
  __shared__ __align__(16) float xs[128*STRIDE];
  __shared__ __align__(16) float hs[256*STRIDE];
  const int tid = threadIdx.x;
  const int n0 = blockIdx.x * TILE;
  for (int i = tid; i < TILE*128; i += 256) {
    const int t = i >> 7, k = i & 127;
    const int n = min(n0 + t, N - 1);
    xs[k*STRIDE + t] = h[(size_t)n*128 + k];
  }
  __syncthreads();
  layer1_silu<128>(xs, w1, b1, hs, tid);
  __syncthreads();
  if (tid < 48) {
    const int t = tid / 3, o = tid - 3*(tid/3);
    float acc = b2[o];
    for (int k = 0; k < 256; ++k)
      acc = fmaf(hs[k*STRIDE + t], w2[k*3 + o], acc);
    const int n = n0 + t;
    if (n < N) out[(size_t)n*3 + o] = acc;
  }
}

// ===========================================================================
extern "C" void kernel_launch(void* const* d_in, const int* in_sizes, int n_in,
                              void* d_out, int out_size, void* d_ws, size_t ws_size,
                              hipStream_t stream)
{
  const float* pos      = (const float*)d_in[0];
  const float* c_in     = (const float*)d_in[1];
  const int*   ati      = (const int*)d_in[2];
  const int*   aci      = (const int*)d_in[3];
  const int*   rci      = (const int*)d_in[4];
  const int*   rsi      = (const int*)d_in[5];
  const int*   snd      = (const int*)d_in[6];
  const int*   rcv      = (const int*)d_in[7];
  const int*   bnd      = (const int*)d_in[8];
  const float* emb_at   = (const float*)d_in[9];
  const float* emb_ac   = (const float*)d_in[10];
  const float* emb_rc   = (const float*)d_in[11];
  const float* emb_ri   = (const float*)d_in[12];
  const float* emb_bond = (const float*)d_in[13];
  const float* nenc_w1  = (const float*)d_in[14];
  const float* nenc_b1  = (const float*)d_in[15];
  const float* nenc_w2  = (const float*)d_in[16];
  const float* nenc_b2  = (const float*)d_in[17];
  const float* eenc_w1  = (const float*)d_in[18];
  const float* eenc_b1  = (const float*)d_in[19];
  const float* eenc_w2  = (const float*)d_in[20];
  const float* eenc_b2  = (const float*)d_in[21];
  const float* msg_w1   = (const float*)d_in[22];
  const float* msg_b1   = (const float*)d_in[23];
  const float* msg_w2   = (const float*)d_in[24];
  const float* msg_b2   = (const float*)d_in[25];
  const float* gate_w   = (const float*)d_in[26];
  const float* gate_b   = (const float*)d_in[27];
  const float* upd_w1   = (const float*)d_in[28];
  const float* upd_b1   = (const float*)d_in[29];
  const float* upd_w2   = (const float*)d_in[30];
  const float* upd_b2   = (const float*)d_in[31];
  const float* head_w1  = (const float*)d_in[32];
  const float* head_b1  = (const float*)d_in[33];
  const float* head_w2  = (const float*)d_in[34];
  const float* head_b2  = (const float*)d_in[35];

  const int N = in_sizes[0] / 3;
  const int E = in_sizes[6];

  // ---- workspace layout (MFMA path) ----
  char* ws = (char*)d_ws;
  float* hbuf           = (float*)ws;           ws += (size_t)N * 128 * sizeof(float);
  unsigned short* hbb   = (unsigned short*)ws;  ws += (size_t)N * 128 * sizeof(unsigned short);
  float* aggbuf         = (float*)ws;           ws += (size_t)N * 128 * sizeof(float);
  float* cutbuf         = (float*)ws;           ws += (size_t)E * sizeof(float);
  unsigned short* packs = (unsigned short*)ws;
  const size_t eenc_w1p_o = 0;
  const size_t eenc_w2p_o = eenc_w1p_o + 16*4*512;
  const size_t msg_w1p_o  = eenc_w2p_o + 8*8*512;
  const size_t msg_w2p_o  = msg_w1p_o + 4*(size_t)(16*12*512);
  const size_t upd_w1p_o  = msg_w2p_o + 4*(size_t)(8*8*512);
  const size_t upd_w2p_o  = upd_w1p_o + 4*(size_t)(16*8*512);
  const size_t packs_end  = upd_w2p_o + 4*(size_t)(8*8*512);
  ws += packs_end * sizeof(unsigned short);
  unsigned short* ebuf_mfma = (unsigned short*)ws;
  const size_t need_mfma = (size_t)(ws - (char*)d_ws) + (size_t)E * 128 * sizeof(unsigned short);

  const int nb_n16 = (N + TILE - 1) / TILE;
  const int n4     = N * 128 / 4;

  if (ws_size >= need_mfma) {
    // ---------------- MFMA path ----------------
    const int nb_e32 = (E + 31) / 32;
    const int nb_n32 = (N + 31) / 32;

    pack_w_kernel<<<96, 256, 0, stream>>>(eenc_w1, packs + eenc_w1p_o, 88, 4, 16);
    pack_w_kernel<<<96, 256, 0, stream>>>(eenc_w2, packs + eenc_w2p_o, 256, 8, 8);
    for (int s = 0; s < 4; ++s) {
      pack_w_kernel<<<96, 256, 0, stream>>>(msg_w1 + (size_t)s*384*256,
          packs + msg_w1p_o + (size_t)s*16*12*512, 384, 12, 16);
      pack_w_kernel<<<96, 256, 0, stream>>>(msg_w2 + (size_t)s*256*128,
          packs + msg_w2p_o + (size_t)s*8*8*512, 256, 8, 8);
      pack_w_kernel<<<96, 256, 0, stream>>>(upd_w1 + (size_t)s*256*256,
          packs + upd_w1p_o + (size_t)s*16*8*512, 256, 8, 16);
      pack_w_kernel<<<96, 256, 0, stream>>>(upd_w2 + (size_t)s*256*128,
          packs + upd_w2p_o + (size_t)s*8*8*512, 256, 8, 8);
    }

    node_enc_kernel<<<nb_n16, 256, 0, stream>>>(
        ati, aci, rci, rsi, emb_at, emb_ac, emb_rc, emb_ri,
        nenc_w1, nenc_b1, nenc_w2, nenc_b2, hbuf, hbb, N);

    edge_enc_mfma<<<nb_e32, 256, 0, stream>>>(
        pos, c_in, snd, rcv, bnd, emb_bond,
        packs + eenc_w1p_o, eenc_b1, packs + eenc_w2p_o, eenc_b2,
        ebuf_mfma, cutbuf, E);

    for (int s = 0; s < 4; ++s) {
      zero_kernel<<<(n4 + 255) / 256, 256, 0, stream>>>((float4*)aggbuf, n4);
      msg_mfma<<<nb_e32, 256, 0, stream>>>(
          hbb, ebuf_mfma, aggbuf, cutbuf, snd, rcv,
          packs + msg_w1p_o + (size_t)s*16*12*512, msg_b1 + (size_t)s*256,
          packs + msg_w2p_o + (size_t)s*8*8*512,   msg_b2 + (size_t)s*128,
          gate_w + (size_t)s*128, gate_b + s, E);
      upd_mfma<<<nb_n32, 256, 0, stream>>>(
          hbuf, hbb, aggbuf,
          packs + upd_w1p_o + (size_t)s*16*8*512, upd_b1 + (size_t)s*256,
          packs + upd_w2p_o + (size_t)s*8*8*512,  upd_b2 + (size_t)s*128, N);
    }

    head_kernel<<<nb_n16, 256, 0, stream>>>(
        hbuf, head_w1, head_b1, head_w2, head_b2, (float*)d_out, N);
  } else {
    // ---------------- fallback: fp32 pipeline (bf16 e) ----------------
    char* ws2 = (char*)d_ws;
    float* hbuf2   = (float*)ws2;   ws2 += (size_t)N * 128 * sizeof(float);
    float* aggbuf2 = (float*)ws2;   ws2 += (size_t)N * 128 * sizeof(float);
    float* cutbuf2 = (float*)ws2;   ws2 += (size_t)E * sizeof(float);
    __hip_bfloat16* ebuf = (__hip_bfloat16*)ws2;
    const int nb_e16 = (E + TILE - 1) / TILE;

    node_enc_kernel<<<nb_n16, 256, 0, stream>>>(
        ati, aci, rci, rsi, emb_at, emb_ac, emb_rc, emb_ri,
        nenc_w1, nenc_b1, nenc_w2, nenc_b2, hbuf2, (unsigned short*)nullptr, N);

    edge_enc_kernel<__hip_bfloat16><<<nb_e16, 256, 0, stream>>>(
        pos, c_in, snd, rcv, bnd, emb_bond,
        eenc_w1, eenc_b1, eenc_w2, eenc_b2, ebuf, cutbuf2, E);

    for (int s = 0; s < 4; ++s) {
      zero_kernel<<<(n4 + 255) / 256, 256, 0, stream>>>((float4*)aggbuf2, n4);
      msg_kernel<__hip_bfloat16><<<nb_e16, 256, 0, stream>>>(
          hbuf2, ebuf, aggbuf2, cutbuf2, snd, rcv,
          msg_w1 + (size_t)s * 384 * 256, msg_b1 + (size_t)s * 256,
          msg_w2 + (size_t)s * 256 * 128, msg_b2 + (size_t)s * 128,
          gate_w + (size_t)s * 128, gate_b + s, E);
      upd_kernel<<<nb_n16, 256, 0, stream>>>(
          hbuf2, aggbuf2,
          upd_w1 + (size_t)s * 256 * 256, upd_b1 + (size_t)s * 256,
          upd_w2 + (size_t)s * 256 * 128, upd_b2 + (size_t)s * 128, N);
    }

    head_kernel<<<nb_n16, 256, 0, stream>>>(
        hbuf2, head_w1, head_b1, head_w2, head_b2, (float*)d_out, N);
  }
}

// Round 5
// 2437.201 us; speedup vs baseline: 5.1973x; 1.0106x over previous
//
#include <hip/hip_runtime.h>
#include <hip/hip_bf16.h>
#include <math.h>

// ---------------------------------------------------------------------------
// MoleculeGNS — MFMA bf16 pipeline v3.
//   - e_old kept in registers across the x1->hsm LDS alias (no global re-read).
//   - __float2bfloat16 HW conversion instead of 3-op manual round.
//   - upd zeros agg rows for the next step (zero_kernel only once).
// Fallback to fp32-VALU pipeline if ws_size too small.
// ---------------------------------------------------------------------------

#define TILE   16
#define STRIDE 20

using short8 = __attribute__((ext_vector_type(8))) short;
using f32x4  = __attribute__((ext_vector_type(4))) float;

__device__ __forceinline__ float silu_f(float x) {
  return x / (1.0f + __expf(-x));
}
__device__ __forceinline__ unsigned short f2b(float x) {
  union { __hip_bfloat16 b; unsigned short u; } v;
  v.b = __float2bfloat16(x);
  return v.u;
}
__device__ __forceinline__ float b2f(unsigned short h) {
  union { unsigned u; float f; } v; v.u = ((unsigned)h) << 16;
  return v.f;
}

// ---------------------------------------------------------------------------
// Weight pack: src row-major [Kreal][N=NF*16] fp32 -> frag-major bf16.
// dst[((nf*KS+kk)*64+l)*8+j] = src[kk*32+(l>>4)*8+j][nf*16+(l&15)], 0 pad.
// ---------------------------------------------------------------------------
__global__ __launch_bounds__(256) void pack_w_kernel(
    const float* __restrict__ src, unsigned short* __restrict__ dst,
    int Kreal, int KS, int NF)
{
  const int N = NF * 16;
  const int total = NF * KS * 512;
  for (int idx = blockIdx.x * 256 + threadIdx.x; idx < total; idx += gridDim.x * 256) {
    const int nf  = idx / (KS * 512);
    const int rem = idx - nf * (KS * 512);
    const int kk  = rem >> 9;
    const int p   = rem & 511;
    const int l   = p >> 3, j = p & 7;
    const int c   = nf * 16 + (l & 15);
    const int k   = kk * 32 + ((l >> 4) << 3) + j;
    dst[idx] = (k < Kreal) ? f2b(src[(size_t)k * N + c]) : (unsigned short)0;
  }
}

// ---------------------------------------------------------------------------
// Layer-1 compute: X1[32][KS1*32] (swizzled bf16 LDS) @ w1p -> acc[8] (regs).
// ---------------------------------------------------------------------------
template<int KS1>
__device__ __forceinline__ void mfma_l1_compute(const unsigned short* __restrict__ x1,
                                                const unsigned short* __restrict__ w1p,
                                                int tid, f32x4 acc[8])
{
  const int w  = tid >> 6;
  const int l  = tid & 63;
  const int lr = l & 15;
  const int lk = (l >> 4) << 3;
  const int RS = KS1 * 32;
  const f32x4 zz = {0.f, 0.f, 0.f, 0.f};
  #pragma unroll
  for (int i = 0; i < 8; ++i) acc[i] = zz;

  for (int kk = 0; kk < KS1; ++kk) {
    short8 af[2];
    #pragma unroll
    for (int mf = 0; mf < 2; ++mf) {
      const int r = mf * 16 + lr;
      const int k = kk * 32 + lk;
      af[mf] = *(const short8*)&x1[r * RS + ((((k >> 3) ^ (r & 7))) << 3)];
    }
    #pragma unroll
    for (int nf = 0; nf < 4; ++nf) {
      const int nfg = w * 4 + nf;
      const short8 bf = *(const short8*)&w1p[(size_t)(((nfg * KS1) + kk) * 64 + l) * 8];
      #pragma unroll
      for (int mf = 0; mf < 2; ++mf)
        acc[mf * 4 + nf] = __builtin_amdgcn_mfma_f32_16x16x32_bf16(af[mf], bf, acc[mf * 4 + nf], 0, 0, 0);
    }
  }
}

// Layer-1 store: bias + silu + bf16 -> hsm[32][256] swizzled (may alias x1;
// caller must barrier between compute and store).
__device__ __forceinline__ void l1_store_silu(const f32x4 acc[8],
                                              const float* __restrict__ b1,
                                              unsigned short* __restrict__ hsm,
                                              int tid)
{
  const int w = tid >> 6, l = tid & 63, lr = l & 15;
  #pragma unroll
  for (int nf = 0; nf < 4; ++nf) {
    const int c = (w * 4 + nf) * 16 + lr;
    const float bias = b1[c];
    #pragma unroll
    for (int mf = 0; mf < 2; ++mf) {
      #pragma unroll
      for (int q = 0; q < 4; ++q) {
        const int r = mf * 16 + ((l >> 4) << 2) + q;
        const float v = silu_f(acc[mf * 4 + nf][q] + bias);
        hsm[r * 256 + (((c >> 3) ^ (r & 7)) << 3) + (c & 7)] = f2b(v);
      }
    }
  }
}

// ---------------------------------------------------------------------------
// Layer 2: hsm[32][256] @ w2p [256,128] + b2 -> acc2[4] (wave cols 32w..).
// ---------------------------------------------------------------------------
__device__ __forceinline__ void mfma_l2(const unsigned short* __restrict__ hsm,
                                        const unsigned short* __restrict__ w2p,
                                        const float* __restrict__ b2,
                                        int tid, f32x4 acc2[4])
{
  const int w  = tid >> 6;
  const int l  = tid & 63;
  const int lr = l & 15;
  const int lk = (l >> 4) << 3;
  const f32x4 zz = {0.f, 0.f, 0.f, 0.f};
  #pragma unroll
  for (int i = 0; i < 4; ++i) acc2[i] = zz;

  for (int kk = 0; kk < 8; ++kk) {
    short8 af[2];
    #pragma unroll
    for (int mf = 0; mf < 2; ++mf) {
      const int r = mf * 16 + lr;
      const int k = kk * 32 + lk;
      af[mf] = *(const short8*)&hsm[r * 256 + (((k >> 3) ^ (r & 7)) << 3)];
    }
    #pragma unroll
    for (int nf2 = 0; nf2 < 2; ++nf2) {
      const int nfg = w * 2 + nf2;
      const short8 bf = *(const short8*)&w2p[(size_t)(((nfg * 8) + kk) * 64 + l) * 8];
      #pragma unroll
      for (int mf = 0; mf < 2; ++mf)
        acc2[mf * 2 + nf2] = __builtin_amdgcn_mfma_f32_16x16x32_bf16(af[mf], bf, acc2[mf * 2 + nf2], 0, 0, 0);
    }
  }
  #pragma unroll
  for (int nf2 = 0; nf2 < 2; ++nf2) {
    const float bias = b2[(w * 2 + nf2) * 16 + lr];
    #pragma unroll
    for (int mf = 0; mf < 2; ++mf) {
      #pragma unroll
      for (int q = 0; q < 4; ++q) acc2[mf * 2 + nf2][q] += bias;
    }
  }
}

// ---------------------------------------------------------------------------
// RMS over d=128 for 32 rows; rsum pre-zeroed; internal barrier.
// ---------------------------------------------------------------------------
__device__ __forceinline__ void rms_reduce(const f32x4 acc2[4], float* rsum,
                                           int tid, float mval[2][2][4])
{
  const int l = tid & 63;
  #pragma unroll
  for (int mf = 0; mf < 2; ++mf) {
    #pragma unroll
    for (int q = 0; q < 4; ++q) {
      float s = acc2[mf * 2][q] * acc2[mf * 2][q]
              + acc2[mf * 2 + 1][q] * acc2[mf * 2 + 1][q];
      s += __shfl_xor(s, 1); s += __shfl_xor(s, 2);
      s += __shfl_xor(s, 4); s += __shfl_xor(s, 8);
      if ((l & 15) == 0)
        atomicAdd(&rsum[mf * 16 + ((l >> 4) << 2) + q], s);
    }
  }
  __syncthreads();
  #pragma unroll
  for (int mf = 0; mf < 2; ++mf) {
    #pragma unroll
    for (int q = 0; q < 4; ++q) {
      const int r = mf * 16 + ((l >> 4) << 2) + q;
      const float inv = rsqrtf(rsum[r] * (1.0f / 128.0f) + 1e-6f);
      #pragma unroll
      for (int nf2 = 0; nf2 < 2; ++nf2)
        mval[mf][nf2][q] = acc2[mf * 2 + nf2][q] * inv;
    }
  }
}

// ---------------------------------------------------------------------------
// Edge encoder (MFMA): geometry -> X1[32][128] -> MLP -> RMS -> e (bf16), cut.
// ---------------------------------------------------------------------------
__global__ __launch_bounds__(256, 5) void edge_enc_mfma(
    const float* __restrict__ pos, const float* __restrict__ c_in,
    const int* __restrict__ snd, const int* __restrict__ rcv,
    const int* __restrict__ bnd, const float* __restrict__ embb,
    const unsigned short* __restrict__ w1p, const float* __restrict__ b1,
    const unsigned short* __restrict__ w2p, const float* __restrict__ b2,
    unsigned short* __restrict__ e_g, float* __restrict__ cutb, int E)
{
  __shared__ __align__(16) unsigned short smem[32 * 256];  // x1 (8KB) / hsm (16KB) aliased
  unsigned short* x1  = smem;
  unsigned short* hsm = smem;
  __shared__ float grbf[32][8];
  __shared__ float gylm[32][9];
  __shared__ float gcut[32];
  __shared__ int   gbond[32];
  __shared__ float rsum[32];
  const int tid = threadIdx.x;
  const int e0  = blockIdx.x * 32;

  if (tid < 32) {
    rsum[tid] = 0.f;
    const int ed = min(e0 + tid, E - 1);
    const int sa = snd[ed], ra = rcv[ed];
    const float ci = c_in[0];
    const float vx = (pos[sa * 3 + 0] - pos[ra * 3 + 0]) / ci;
    const float vy = (pos[sa * 3 + 1] - pos[ra * 3 + 1]) / ci;
    const float vz = (pos[sa * 3 + 2] - pos[ra * 3 + 2]) / ci;
    const float r  = sqrtf(vx * vx + vy * vy + vz * vz + 1e-12f);
    const float ir = 1.0f / r;
    const float ux = vx * ir, uy = vy * ir, uz = vz * ir;
    const float PI = 3.14159265358979323846f;
    const float pr = PI * r * 0.2f;
    const float c0 = 0.632455532033675866f;   // sqrt(2/5)
    #pragma unroll
    for (int n = 0; n < 8; ++n)
      grbf[tid][n] = c0 * sinf((float)(n + 1) * pr) * ir;
    const float cv = 0.5f * (cosf(PI * fminf(r, 5.0f) * 0.2f) + 1.0f)
                   * (r < 5.0f ? 1.0f : 0.0f);
    gcut[tid] = cv;
    if (e0 + tid < E) cutb[e0 + tid] = cv;
    const float s3  = 1.7320508075688772f;
    const float s5  = 2.2360679774997896f;
    const float s15 = 3.8729833462074170f;
    gylm[tid][0] = 1.0f;
    gylm[tid][1] = s3 * ux; gylm[tid][2] = s3 * uy; gylm[tid][3] = s3 * uz;
    gylm[tid][4] = s15 * ux * uy; gylm[tid][5] = s15 * uy * uz;
    gylm[tid][6] = 0.5f * s5 * (3.0f * uz * uz - 1.0f);
    gylm[tid][7] = s15 * ux * uz;
    gylm[tid][8] = 0.5f * s15 * (ux * ux - uy * uy);
    gbond[tid] = bnd[ed];
  }
  __syncthreads();
  for (int i = tid; i < 32 * 16; i += 256) {
    const int r = i >> 4, g = i & 15;
    union { short8 v; unsigned short u[8]; } t;
    #pragma unroll
    for (int j = 0; j < 8; ++j) {
      const int k = g * 8 + j;
      float v;
      if (k < 72) { const int n = k / 9, mm = k - 9 * n; v = grbf[r][n] * gylm[r][mm] * gcut[r]; }
      else if (k < 88) v = embb[gbond[r] * 16 + (k - 72)];
      else v = 0.f;
      t.u[j] = f2b(v);
    }
    *(short8*)&x1[r * 128 + ((g ^ (r & 7)) << 3)] = t.v;
  }
  __syncthreads();
  f32x4 acc1[8];
  mfma_l1_compute<4>(x1, w1p, tid, acc1);
  __syncthreads();                        // x1 dead; hsm aliases it
  l1_store_silu(acc1, b1, hsm, tid);
  __syncthreads();
  f32x4 acc2[4];
  mfma_l2(hsm, w2p, b2, tid, acc2);
  float mval[2][2][4];
  rms_reduce(acc2, rsum, tid, mval);
  const int l = tid & 63, w = tid >> 6, lr = l & 15;
  #pragma unroll
  for (int mf = 0; mf < 2; ++mf) {
    #pragma unroll
    for (int q = 0; q < 4; ++q) {
      const int r = mf * 16 + ((l >> 4) << 2) + q;
      const int ed = e0 + r;
      if (ed < E) {
        #pragma unroll
        for (int nf2 = 0; nf2 < 2; ++nf2) {
          const int c2 = (w * 2 + nf2) * 16 + lr;
          e_g[(size_t)ed * 128 + c2] = f2b(mval[mf][nf2][q]);
        }
      }
    }
  }
}

// ---------------------------------------------------------------------------
// Message step (MFMA): X1 = [hb_s | hb_r | e] (pure short8 copies) -> MLP
// -> RMS -> gate, e+=m, agg atomics.  e_old carried in regs across the alias.
// ---------------------------------------------------------------------------
__global__ __launch_bounds__(256, 5) void msg_mfma(
    const unsigned short* __restrict__ hb, unsigned short* __restrict__ e_g,
    float* __restrict__ agg, const float* __restrict__ cutb,
    const int* __restrict__ snd, const int* __restrict__ rcv,
    const unsigned short* __restrict__ w1p, const float* __restrict__ b1,
    const unsigned short* __restrict__ w2p, const float* __restrict__ b2,
    const float* __restrict__ gw, const float* __restrict__ gb, int E)
{
  __shared__ __align__(16) unsigned short smem[32 * 384];  // x1 (24KB) / hsm (16KB) aliased
  unsigned short* x1  = smem;
  unsigned short* hsm = smem;
  __shared__ int   snd_s[32], rcv_s[32];
  __shared__ float cut_s[32];
  __shared__ float rsum[32], gsum[32];
  const int tid = threadIdx.x;
  const int e0  = blockIdx.x * 32;

  if (tid < 32) {
    rsum[tid] = 0.f; gsum[tid] = 0.f;
    const int ed = min(e0 + tid, E - 1);
    snd_s[tid] = snd[ed]; rcv_s[tid] = rcv[ed]; cut_s[tid] = cutb[ed];
  }
  __syncthreads();
  for (int i = tid; i < 32 * 48; i += 256) {
    const int r = i / 48, g = i - r * 48;
    short8 t;
    if (g < 32) {
      const int node = (g < 16) ? snd_s[r] : rcv_s[r];
      t = *(const short8*)&hb[(size_t)node * 128 + (g & 15) * 8];
    } else {
      const int ed = min(e0 + r, E - 1);
      t = *(const short8*)&e_g[(size_t)ed * 128 + (g - 32) * 8];
    }
    *(short8*)&x1[r * 384 + ((g ^ (r & 7)) << 3)] = t;
  }
  __syncthreads();
  f32x4 acc1[8];
  mfma_l1_compute<12>(x1, w1p, tid, acc1);

  // stash e_old (epilogue needs it) before hsm overwrites x1
  const int l = tid & 63, w = tid >> 6, lr = l & 15;
  float eold[16];
  {
    int idx = 0;
    #pragma unroll
    for (int mf = 0; mf < 2; ++mf) {
      #pragma unroll
      for (int q = 0; q < 4; ++q) {
        const int r = mf * 16 + ((l >> 4) << 2) + q;
        #pragma unroll
        for (int nf2 = 0; nf2 < 2; ++nf2) {
          const int k = 256 + (w * 2 + nf2) * 16 + lr;
          eold[idx++] = b2f(x1[r * 384 + (((k >> 3) ^ (r & 7)) << 3) + (k & 7)]);
        }
      }
    }
  }
  __syncthreads();                        // x1 dead; hsm aliases it
  l1_store_silu(acc1, b1, hsm, tid);
  __syncthreads();
  f32x4 acc2[4];
  mfma_l2(hsm, w2p, b2, tid, acc2);
  float mval[2][2][4];
  rms_reduce(acc2, rsum, tid, mval);

  const float gw0 = gw[(w * 2 + 0) * 16 + lr];
  const float gw1 = gw[(w * 2 + 1) * 16 + lr];
  #pragma unroll
  for (int mf = 0; mf < 2; ++mf) {
    #pragma unroll
    for (int q = 0; q < 4; ++q) {
      float p = mval[mf][0][q] * gw0 + mval[mf][1][q] * gw1;
      p += __shfl_xor(p, 1); p += __shfl_xor(p, 2);
      p += __shfl_xor(p, 4); p += __shfl_xor(p, 8);
      if ((l & 15) == 0)
        atomicAdd(&gsum[mf * 16 + ((l >> 4) << 2) + q], p);
    }
  }
  __syncthreads();
  const float gbv = gb[0];
  {
    int idx = 0;
    #pragma unroll
    for (int mf = 0; mf < 2; ++mf) {
      #pragma unroll
      for (int q = 0; q < 4; ++q) {
        const int r = mf * 16 + ((l >> 4) << 2) + q;
        const int ed = e0 + r;
        if (ed < E) {
          const float gr = cut_s[r] / (1.0f + __expf(-(gsum[r] + gbv)));
          const int rv = rcv_s[r];
          #pragma unroll
          for (int nf2 = 0; nf2 < 2; ++nf2) {
            const int c2 = (w * 2 + nf2) * 16 + lr;
            const float m = mval[mf][nf2][q];
            e_g[(size_t)ed * 128 + c2] = f2b(eold[idx] + m);
            atomicAdd(&agg[(size_t)rv * 128 + c2], m * gr);
            ++idx;
          }
        } else {
          idx += 2;
        }
      }
    }
  }
}

// ---------------------------------------------------------------------------
// Update step (MFMA): X1 = [hb | agg] -> MLP -> RMS -> h += m; hb mirror;
// zeros agg rows for the next step.
// ---------------------------------------------------------------------------
__global__ __launch_bounds__(256, 5) void upd_mfma(
    float* __restrict__ h, unsigned short* __restrict__ hb,
    float* __restrict__ agg,
    const unsigned short* __restrict__ w1p, const float* __restrict__ b1,
    const unsigned short* __restrict__ w2p, const float* __restrict__ b2,
    int N)
{
  __shared__ __align__(16) unsigned short smem[32 * 256];  // x1 (16KB) / hsm (16KB) aliased
  unsigned short* x1  = smem;
  unsigned short* hsm = smem;
  __shared__ float rsum[32];
  const int tid = threadIdx.x;
  const int n0  = blockIdx.x * 32;
  if (tid < 32) rsum[tid] = 0.f;
  __syncthreads();
  for (int i = tid; i < 32 * 32; i += 256) {
    const int r = i >> 5, g = i & 31;
    const int n = min(n0 + r, N - 1);
    short8 t;
    if (g < 16) {
      t = *(const short8*)&hb[(size_t)n * 128 + g * 8];
    } else {
      const float4 f0 = *(const float4*)&agg[(size_t)n * 128 + (g - 16) * 8];
      const float4 f1 = *(const float4*)&agg[(size_t)n * 128 + (g - 16) * 8 + 4];
      union { short8 v; unsigned short u[8]; } tt;
      tt.u[0] = f2b(f0.x); tt.u[1] = f2b(f0.y); tt.u[2] = f2b(f0.z); tt.u[3] = f2b(f0.w);
      tt.u[4] = f2b(f1.x); tt.u[5] = f2b(f1.y); tt.u[6] = f2b(f1.z); tt.u[7] = f2b(f1.w);
      t = tt.v;
    }
    *(short8*)&x1[r * 256 + ((g ^ (r & 7)) << 3)] = t;
  }
  __syncthreads();
  // zero this block's agg rows for the next step (all reads complete)
  for (int i = tid; i < 1024; i += 256) {
    const int r = i >> 5, c4 = i & 31;
    const int n = n0 + r;
    if (n < N) *(float4*)&agg[(size_t)n * 128 + c4 * 4] = make_float4(0.f, 0.f, 0.f, 0.f);
  }
  f32x4 acc1[8];
  mfma_l1_compute<8>(x1, w1p, tid, acc1);
  __syncthreads();
  l1_store_silu(acc1, b1, hsm, tid);
  __syncthreads();
  f32x4 acc2[4];
  mfma_l2(hsm, w2p, b2, tid, acc2);
  float mval[2][2][4];
  rms_reduce(acc2, rsum, tid, mval);
  const int l = tid & 63, w = tid >> 6, lr = l & 15;
  #pragma unroll
  for (int mf = 0; mf < 2; ++mf) {
    #pragma unroll
    for (int q = 0; q < 4; ++q) {
      const int r = mf * 16 + ((l >> 4) << 2) + q;
      const int n = n0 + r;
      if (n < N) {
        #pragma unroll
        for (int nf2 = 0; nf2 < 2; ++nf2) {
          const int c2 = (w * 2 + nf2) * 16 + lr;
          const float nh = h[(size_t)n * 128 + c2] + mval[mf][nf2][q];
          h[(size_t)n * 128 + c2]  = nh;
          hb[(size_t)n * 128 + c2] = f2b(nh);
        }
      }
    }
  }
}

// ===========================================================================
// fp32 pipeline (node/head kernels + full fallback).
// ===========================================================================

__device__ __forceinline__ float loadE(const float* p)          { return *p; }
__device__ __forceinline__ float loadE(const __hip_bfloat16* p) { return __bfloat162float(*p); }
__device__ __forceinline__ void  storeE(float* p, float v)          { *p = v; }
__device__ __forceinline__ void  storeE(__hip_bfloat16* p, float v) { *p = __float2bfloat16(v); }

template<int K1>
__device__ __forceinline__ void layer1_silu(const float* __restrict__ xs,
                                            const float* __restrict__ w1,
                                            const float* __restrict__ b1,
                                            float* __restrict__ hs, int tid)
{
  const int jh = tid & 127;
  const int tp = tid >> 7;
  const int tbase = 8 * tp;
  float a[8] = {0,0,0,0,0,0,0,0};
  float b[8] = {0,0,0,0,0,0,0,0};
  const float* wp = w1 + jh;
  for (int k = 0; k < K1; ++k) {
    const float4 x0 = *(const float4*)&xs[k*STRIDE + tbase];
    const float4 x1 = *(const float4*)&xs[k*STRIDE + tbase + 4];
    const float wa = wp[k*256];
    const float wb = wp[k*256 + 128];
    a[0] = fmaf(x0.x, wa, a[0]); a[1] = fmaf(x0.y, wa, a[1]);
    a[2] = fmaf(x0.z, wa, a[2]); a[3] = fmaf(x0.w, wa, a[3]);
    a[4] = fmaf(x1.x, wa, a[4]); a[5] = fmaf(x1.y, wa, a[5]);
    a[6] = fmaf(x1.z, wa, a[6]); a[7] = fmaf(x1.w, wa, a[7]);
    b[0] = fmaf(x0.x, wb, b[0]); b[1] = fmaf(x0.y, wb, b[1]);
    b[2] = fmaf(x0.z, wb, b[2]); b[3] = fmaf(x0.w, wb, b[3]);
    b[4] = fmaf(x1.x, wb, b[4]); b[5] = fmaf(x1.y, wb, b[5]);
    b[6] = fmaf(x1.z, wb, b[6]); b[7] = fmaf(x1.w, wb, b[7]);
  }
  const float ba = b1[jh];
  const float bb = b1[jh + 128];
  float4 oa0, oa1, ob0, ob1;
  oa0.x = silu_f(a[0] + ba); oa0.y = silu_f(a[1] + ba);
  oa0.z = silu_f(a[2] + ba); oa0.w = silu_f(a[3] + ba);
  oa1.x = silu_f(a[4] + ba); oa1.y = silu_f(a[5] + ba);
  oa1.z = silu_f(a[6] + ba); oa1.w = silu_f(a[7] + ba);
  ob0.x = silu_f(b[0] + bb); ob0.y = silu_f(b[1] + bb);
  ob0.z = silu_f(b[2] + bb); ob0.w = silu_f(b[3] + bb);
  ob1.x = silu_f(b[4] + bb); ob1.y = silu_f(b[5] + bb);
  ob1.z = silu_f(b[6] + bb); ob1.w = silu_f(b[7] + bb);
  *(float4*)&hs[jh*STRIDE + tbase]           = oa0;
  *(float4*)&hs[jh*STRIDE + tbase + 4]       = oa1;
  *(float4*)&hs[(jh+128)*STRIDE + tbase]     = ob0;
  *(float4*)&hs[(jh+128)*STRIDE + tbase + 4] = ob1;
}

__device__ __forceinline__ void layer2_bias(const float* __restrict__ hs,
                                            const float* __restrict__ w2,
                                            const float* __restrict__ b2,
                                            int tid, float cA[4], float cB[4])
{
  const int dh = tid & 63;
  const int tq = tid >> 6;
  const int tbase = 4 * tq;
  cA[0]=cA[1]=cA[2]=cA[3]=0.0f;
  cB[0]=cB[1]=cB[2]=cB[3]=0.0f;
  const float* wp = w2 + dh;
  for (int k = 0; k < 256; ++k) {
    const float4 hv = *(const float4*)&hs[k*STRIDE + tbase];
    const float wa = wp[k*128];
    const float wb = wp[k*128 + 64];
    cA[0] = fmaf(hv.x, wa, cA[0]); cA[1] = fmaf(hv.y, wa, cA[1]);
    cA[2] = fmaf(hv.z, wa, cA[2]); cA[3] = fmaf(hv.w, wa, cA[3]);
    cB[0] = fmaf(hv.x, wb, cB[0]); cB[1] = fmaf(hv.y, wb, cB[1]);
    cB[2] = fmaf(hv.z, wb, cB[2]); cB[3] = fmaf(hv.w, wb, cB[3]);
  }
  const float b2a = b2[dh];
  const float b2b = b2[dh + 64];
  #pragma unroll
  for (int tt = 0; tt < 4; ++tt) { cA[tt] += b2a; cB[tt] += b2b; }
}

__device__ __forceinline__ void rms4(float cA[4], float cB[4])
{
  float s[4];
  #pragma unroll
  for (int tt = 0; tt < 4; ++tt) s[tt] = cA[tt]*cA[tt] + cB[tt]*cB[tt];
  #pragma unroll
  for (int off = 32; off; off >>= 1) {
    #pragma unroll
    for (int tt = 0; tt < 4; ++tt) s[tt] += __shfl_xor(s[tt], off);
  }
  #pragma unroll
  for (int tt = 0; tt < 4; ++tt) {
    const float inv = rsqrtf(s[tt] * (1.0f/128.0f) + 1e-6f);
    cA[tt] *= inv; cB[tt] *= inv;
  }
}

__global__ __launch_bounds__(256) void zero_kernel(float4* __restrict__ p, int n4)
{
  const int i = blockIdx.x * 256 + threadIdx.x;
  if (i < n4) p[i] = make_float4(0.f, 0.f, 0.f, 0.f);
}

// Node encoder (fp32) + optional bf16 mirror.
__global__ __launch_bounds__(256) void node_enc_kernel(
    const int* __restrict__ ati, const int* __restrict__ aci,
    const int* __restrict__ rci, const int* __restrict__ rsi,
    const float* __restrict__ emb_at, const float* __restrict__ emb_ac,
    const float* __restrict__ emb_rc, const float* __restrict__ emb_ri,
    const float* __restrict__ w1, const float* __restrict__ b1,
    const float* __restrict__ w2, const float* __restrict__ b2,
    float* __restrict__ h, unsigned short* __restrict__ hb, int N)
{
  __shared__ __align__(16) float xs[128*STRIDE];
  __shared__ __align__(16) float hs[256*STRIDE];
  __shared__ int idx_s[4][TILE];
  const int tid = threadIdx.x;
  const int n0 = blockIdx.x * TILE;
  if (tid < TILE) {
    const int n = min(n0 + tid, N - 1);
    idx_s[0][tid] = ati[n]; idx_s[1][tid] = aci[n];
    idx_s[2][tid] = rci[n]; idx_s[3][tid] = rsi[n];
  }
  __syncthreads();
  for (int i = tid; i < TILE*128; i += 256) {
    const int t = i >> 7, k = i & 127;
    const int seg = k >> 5, kk = k & 31;
    const float* tab = (seg == 0) ? emb_at : (seg == 1) ? emb_ac
                     : (seg == 2) ? emb_rc : emb_ri;
    xs[k*STRIDE + t] = tab[idx_s[seg][t]*32 + kk];
  }
  __syncthreads();
  layer1_silu<128>(xs, w1, b1, hs, tid);
  __syncthreads();
  float cA[4], cB[4];
  layer2_bias(hs, w2, b2, tid, cA, cB);
  rms4(cA, cB);
  const int dh = tid & 63, tq = tid >> 6;
  #pragma unroll
  for (int tt = 0; tt < 4; ++tt) {
    const int n = n0 + 4*tq + tt;
    if (n < N) {
      h[(size_t)n*128 + dh]      = cA[tt];
      h[(size_t)n*128 + dh + 64] = cB[tt];
      if (hb) {
        hb[(size_t)n*128 + dh]      = f2b(cA[tt]);
        hb[(size_t)n*128 + dh + 64] = f2b(cB[tt]);
      }
    }
  }
}

template<typename ET>
__global__ __launch_bounds__(256) void edge_enc_kernel(
    const float* __restrict__ pos, const float* __restrict__ c_in,
    const int* __restrict__ snd, const int* __restrict__ rcv,
    const int* __restrict__ bnd, const float* __restrict__ emb_bond,
    const float* __restrict__ w1, const float* __restrict__ b1,
    const float* __restrict__ w2, const float* __restrict__ b2,
    ET* __restrict__ e, float* __restrict__ cutb, int E)
{
  __shared__ __align__(16) float xs[88*STRIDE];
  __shared__ __align__(16) float hs[256*STRIDE];
  __shared__ float grbf[TILE][8];
  __shared__ float gylm[TILE][9];
  __shared__ float gcut[TILE];
  __shared__ int   gbond[TILE];
  const int tid = threadIdx.x;
  const int e0 = blockIdx.x * TILE;
  if (tid < TILE) {
    const int ed = min(e0 + tid, E - 1);
    const int sa = snd[ed], ra = rcv[ed];
    const float ci = c_in[0];
    const float vx = (pos[sa*3+0] - pos[ra*3+0]) / ci;
    const float vy = (pos[sa*3+1] - pos[ra*3+1]) / ci;
    const float vz = (pos[sa*3+2] - pos[ra*3+2]) / ci;
    const float r  = sqrtf(vx*vx + vy*vy + vz*vz + 1e-12f);
    const float ir = 1.0f / r;
    const float ux = vx*ir, uy = vy*ir, uz = vz*ir;
    const float PI = 3.14159265358979323846f;
    const float pr = PI * r * 0.2f;
    const float c0 = 0.632455532033675866f;
    #pragma unroll
    for (int n = 0; n < 8; ++n)
      grbf[tid][n] = c0 * sinf((float)(n + 1) * pr) * ir;
    const float cv = 0.5f * (cosf(PI * fminf(r, 5.0f) * 0.2f) + 1.0f)
                   * (r < 5.0f ? 1.0f : 0.0f);
    gcut[tid] = cv;
    cutb[ed] = cv;
    const float s3  = 1.7320508075688772f;
    const float s5  = 2.2360679774997896f;
    const float s15 = 3.8729833462074170f;
    gylm[tid][0] = 1.0f;
    gylm[tid][1] = s3*ux; gylm[tid][2] = s3*uy; gylm[tid][3] = s3*uz;
    gylm[tid][4] = s15*ux*uy; gylm[tid][5] = s15*uy*uz;
    gylm[tid][6] = 0.5f*s5*(3.0f*uz*uz - 1.0f);
    gylm[tid][7] = s15*ux*uz;
    gylm[tid][8] = 0.5f*s15*(ux*ux - uy*uy);
    gbond[tid] = bnd[ed];
  }
  __syncthreads();
  for (int i = tid; i < TILE*88; i += 256) {
    const int t = i & 15, k = i >> 4;
    float v;
    if (k < 72) {
      const int n = k / 9, m = k - 9*n;
      v = grbf[t][n] * gylm[t][m] * gcut[t];
    } else {
      v = emb_bond[gbond[t]*16 + (k - 72)];
    }
    xs[k*STRIDE + t] = v;
  }
  __syncthreads();
  layer1_silu<88>(xs, w1, b1, hs, tid);
  __syncthreads();
  float cA[4], cB[4];
  layer2_bias(hs, w2, b2, tid, cA, cB);
  rms4(cA, cB);
  const int dh = tid & 63, tq = tid >> 6;
  #pragma unroll
  for (int tt = 0; tt < 4; ++tt) {
    const int ed = e0 + 4*tq + tt;
    if (ed < E) {
      storeE(&e[(size_t)ed*128 + dh],      cA[tt]);
      storeE(&e[(size_t)ed*128 + dh + 64], cB[tt]);
    }
  }
}

template<typename ET>
__global__ __launch_bounds__(256) void msg_kernel(
    const float* __restrict__ h, ET* __restrict__ e,
    float* __restrict__ agg, const float* __restrict__ cutb,
    const int* __restrict__ snd, const int* __restrict__ rcv,
    const float* __restrict__ w1, const float* __restrict__ b1,
    const float* __restrict__ w2, const float* __restrict__ b2,
    const float* __restrict__ gw, const float* __restrict__ gb,
    int E)
{
  __shared__ __align__(16) float xs[384*STRIDE];
  __shared__ __align__(16) float hs[256*STRIDE];
  __shared__ int   snd_s[TILE], rcv_s[TILE];
  __shared__ float cut_s[TILE];
  const int tid = threadIdx.x;
  const int e0 = blockIdx.x * TILE;
  if (tid < TILE) {
    const int ed = min(e0 + tid, E - 1);
    snd_s[tid] = snd[ed]; rcv_s[tid] = rcv[ed]; cut_s[tid] = cutb[ed];
  }
  __syncthreads();
  for (int i = tid; i < TILE*384; i += 256) {
    const int t = i / 384, k = i - t*384;
    float v;
    if (k < 128)      v = h[(size_t)snd_s[t]*128 + k];
    else if (k < 256) v = h[(size_t)rcv_s[t]*128 + (k - 128)];
    else {
      const int ed = min(e0 + t, E - 1);
      v = loadE(&e[(size_t)ed*128 + (k - 256)]);
    }
    xs[k*STRIDE + t] = v;
  }
  __syncthreads();
  layer1_silu<384>(xs, w1, b1, hs, tid);
  __syncthreads();
  float cA[4], cB[4];
  layer2_bias(hs, w2, b2, tid, cA, cB);
  rms4(cA, cB);
  const int dh = tid & 63, tq = tid >> 6;
  const float gwa = gw[dh], gwb = gw[dh + 64];
  const float gbv = gb[0];
  float gv[4];
  #pragma unroll
  for (int tt = 0; tt < 4; ++tt) gv[tt] = cA[tt]*gwa + cB[tt]*gwb;
  #pragma unroll
  for (int off = 32; off; off >>= 1) {
    #pragma unroll
    for (int tt = 0; tt < 4; ++tt) gv[tt] += __shfl_xor(gv[tt], off);
  }
  #pragma unroll
  for (int tt = 0; tt < 4; ++tt) {
    const int t = 4*tq + tt;
    const int ed = e0 + t;
    if (ed < E) {
      const float g = cut_s[t] / (1.0f + __expf(-(gv[tt] + gbv)));
      const float eoA = xs[(256 + dh)*STRIDE + t];
      const float eoB = xs[(256 + dh + 64)*STRIDE + t];
      storeE(&e[(size_t)ed*128 + dh],      eoA + cA[tt]);
      storeE(&e[(size_t)ed*128 + dh + 64], eoB + cB[tt]);
      const int rv = rcv_s[t];
      atomicAdd(&agg[(size_t)rv*128 + dh],      cA[tt]*g);
      atomicAdd(&agg[(size_t)rv*128 + dh + 64], cB[tt]*g);
    }
  }
}

__global__ __launch_bounds__(256) void upd_kernel(
    float* __restrict__ h, const float* __restrict__ agg,
    const float* __restrict__ w1, const float* __restrict__ b1,
    const float* __restrict__ w2, const float* __restrict__ b2,
    int N)
{
  __shared__ __align__(16) float xs[256*STRIDE];
  __shared__ __align__(16) float hs[256*STRIDE];
  const int tid = threadIdx.x;
  const int n0 = blockIdx.x * TILE;
  for (int i = tid; i < TILE*256; i += 256) {
    const int t = i >> 8, k = i & 255;
    const int n = min(n0 + t, N - 1);
    const float v = (k < 128) ? h[(size_t)n*128 + k]
                              : agg[(size_t)n*128 + (k - 128)];
    xs[k*STRIDE + t] = v;
  }
  __syncthreads();
  layer1_silu<256>(xs, w1, b1, hs, tid);
  __syncthreads();
  float cA[4], cB[4];
  layer2_bias(hs, w2, b2, tid, cA, cB);
  rms4(cA, cB);
  const int dh = tid & 63, tq = tid >> 6;
  #pragma unroll
  for (int tt = 0; tt < 4; ++tt) {
    const int t = 4*tq + tt;
    const int n = n0 + t;
    if (n < N) {
      h[(size_t)n*128 + dh]      = xs[dh*STRIDE + t] + cA[tt];
      h[(size_t)n*128 + dh + 64] = xs[(dh + 64)*STRIDE + t] + cB[tt];
    }
  }
}

__global__ __launch_bounds__(256) void head_kernel(
    const float* __restrict__ h,
    const float* __restrict__ w1, const float* __restrict__ b1,
    const float* __restrict__ w2, const float* __restrict__ b2,
    float* __restrict__ out, int N)
{
  __shared__ __align__(16) float xs[128*STRIDE];
  __shared__ __align__(16) float hs[256*STRIDE];
  const int tid = threadIdx.x;
  const int n0 = blockIdx.x * TILE;
  for (int i = tid; i < TILE*128; i += 256) {
    const int t = i >> 7, k = i & 127;
    const int n = min(n0 + t, N - 1);
    xs[k*STRIDE + t] = h[(size_t)n*128 + k];
  }
  __syncthreads();
  layer1_silu<128>(xs, w1, b1, hs, tid);
  __syncthreads();
  if (tid < 48) {
    const int t = tid / 3, o = tid - 3*(tid/3);
    float acc = b2[o];
    for (int k = 0; k < 256; ++k)
      acc = fmaf(hs[k*STRIDE + t], w2[k*3 + o], acc);
    const int n = n0 + t;
    if (n < N) out[(size_t)n*3 + o] = acc;
  }
}

// ===========================================================================
extern "C" void kernel_launch(void* const* d_in, const int* in_sizes, int n_in,
                              void* d_out, int out_size, void* d_ws, size_t ws_size,
                              hipStream_t stream)
{
  const float* pos      = (const float*)d_in[0];
  const float* c_in     = (const float*)d_in[1];
  const int*   ati      = (const int*)d_in[2];
  const int*   aci      = (const int*)d_in[3];
  const int*   rci      = (const int*)d_in[4];
  const int*   rsi      = (const int*)d_in[5];
  const int*   snd      = (const int*)d_in[6];
  const int*   rcv      = (const int*)d_in[7];
  const int*   bnd      = (const int*)d_in[8];
  const float* emb_at   = (const float*)d_in[9];
  const float* emb_ac   = (const float*)d_in[10];
  const float* emb_rc   = (const float*)d_in[11];
  const float* emb_ri   = (const float*)d_in[12];
  const float* emb_bond = (const float*)d_in[13];
  const float* nenc_w1  = (const float*)d_in[14];
  const float* nenc_b1  = (const float*)d_in[15];
  const float* nenc_w2  = (const float*)d_in[16];
  const float* nenc_b2  = (const float*)d_in[17];
  const float* eenc_w1  = (const float*)d_in[18];
  const float* eenc_b1  = (const float*)d_in[19];
  const float* eenc_w2  = (const float*)d_in[20];
  const float* eenc_b2  = (const float*)d_in[21];
  const float* msg_w1   = (const float*)d_in[22];
  const float* msg_b1   = (const float*)d_in[23];
  const float* msg_w2   = (const float*)d_in[24];
  const float* msg_b2   = (const float*)d_in[25];
  const float* gate_w   = (const float*)d_in[26];
  const float* gate_b   = (const float*)d_in[27];
  const float* upd_w1   = (const float*)d_in[28];
  const float* upd_b1   = (const float*)d_in[29];
  const float* upd_w2   = (const float*)d_in[30];
  const float* upd_b2   = (const float*)d_in[31];
  const float* head_w1  = (const float*)d_in[32];
  const float* head_b1  = (const float*)d_in[33];
  const float* head_w2  = (const float*)d_in[34];
  const float* head_b2  = (const float*)d_in[35];

  const int N = in_sizes[0] / 3;
  const int E = in_sizes[6];

  // ---- workspace layout (MFMA path) ----
  char* ws = (char*)d_ws;
  float* hbuf           = (float*)ws;           ws += (size_t)N * 128 * sizeof(float);
  unsigned short* hbb   = (unsigned short*)ws;  ws += (size_t)N * 128 * sizeof(unsigned short);
  float* aggbuf         = (float*)ws;           ws += (size_t)N * 128 * sizeof(float);
  float* cutbuf         = (float*)ws;           ws += (size_t)E * sizeof(float);
  unsigned short* packs = (unsigned short*)ws;
  const size_t eenc_w1p_o = 0;
  const size_t eenc_w2p_o = eenc_w1p_o + 16*4*512;
  const size_t msg_w1p_o  = eenc_w2p_o + 8*8*512;
  const size_t msg_w2p_o  = msg_w1p_o + 4*(size_t)(16*12*512);
  const size_t upd_w1p_o  = msg_w2p_o + 4*(size_t)(8*8*512);
  const size_t upd_w2p_o  = upd_w1p_o + 4*(size_t)(16*8*512);
  const size_t packs_end  = upd_w2p_o + 4*(size_t)(8*8*512);
  ws += packs_end * sizeof(unsigned short);
  unsigned short* ebuf_mfma = (unsigned short*)ws;
  const size_t need_mfma = (size_t)(ws - (char*)d_ws) + (size_t)E * 128 * sizeof(unsigned short);

  const int nb_n16 = (N + TILE - 1) / TILE;
  const int n4     = N * 128 / 4;

  if (ws_size >= need_mfma) {
    // ---------------- MFMA path ----------------
    const int nb_e32 = (E + 31) / 32;
    const int nb_n32 = (N + 31) / 32;

    pack_w_kernel<<<96, 256, 0, stream>>>(eenc_w1, packs + eenc_w1p_o, 88, 4, 16);
    pack_w_kernel<<<96, 256, 0, stream>>>(eenc_w2, packs + eenc_w2p_o, 256, 8, 8);
    for (int s = 0; s < 4; ++s) {
      pack_w_kernel<<<96, 256, 0, stream>>>(msg_w1 + (size_t)s*384*256,
          packs + msg_w1p_o + (size_t)s*16*12*512, 384, 12, 16);
      pack_w_kernel<<<96, 256, 0, stream>>>(msg_w2 + (size_t)s*256*128,
          packs + msg_w2p_o + (size_t)s*8*8*512, 256, 8, 8);
      pack_w_kernel<<<96, 256, 0, stream>>>(upd_w1 + (size_t)s*256*256,
          packs + upd_w1p_o + (size_t)s*16*8*512, 256, 8, 16);
      pack_w_kernel<<<96, 256, 0, stream>>>(upd_w2 + (size_t)s*256*128,
          packs + upd_w2p_o + (size_t)s*8*8*512, 256, 8, 8);
    }

    node_enc_kernel<<<nb_n16, 256, 0, stream>>>(
        ati, aci, rci, rsi, emb_at, emb_ac, emb_rc, emb_ri,
        nenc_w1, nenc_b1, nenc_w2, nenc_b2, hbuf, hbb, N);

    edge_enc_mfma<<<nb_e32, 256, 0, stream>>>(
        pos, c_in, snd, rcv, bnd, emb_bond,
        packs + eenc_w1p_o, eenc_b1, packs + eenc_w2p_o, eenc_b2,
        ebuf_mfma, cutbuf, E);

    // agg starts poisoned (0xAA): zero once; upd re-zeros for later steps.
    zero_kernel<<<(n4 + 255) / 256, 256, 0, stream>>>((float4*)aggbuf, n4);

    for (int s = 0; s < 4; ++s) {
      msg_mfma<<<nb_e32, 256, 0, stream>>>(
          hbb, ebuf_mfma, aggbuf, cutbuf, snd, rcv,
          packs + msg_w1p_o + (size_t)s*16*12*512, msg_b1 + (size_t)s*256,
          packs + msg_w2p_o + (size_t)s*8*8*512,   msg_b2 + (size_t)s*128,
          gate_w + (size_t)s*128, gate_b + s, E);
      upd_mfma<<<nb_n32, 256, 0, stream>>>(
          hbuf, hbb, aggbuf,
          packs + upd_w1p_o + (size_t)s*16*8*512, upd_b1 + (size_t)s*256,
          packs + upd_w2p_o + (size_t)s*8*8*512,  upd_b2 + (size_t)s*128, N);
    }

    head_kernel<<<nb_n16, 256, 0, stream>>>(
        hbuf, head_w1, head_b1, head_w2, head_b2, (float*)d_out, N);
  } else {
    // ---------------- fallback: fp32 pipeline (bf16 e) ----------------
    char* ws2 = (char*)d_ws;
    float* hbuf2   = (float*)ws2;   ws2 += (size_t)N * 128 * sizeof(float);
    float* aggbuf2 = (float*)ws2;   ws2 += (size_t)N * 128 * sizeof(float);
    float* cutbuf2 = (float*)ws2;   ws2 += (size_t)E * sizeof(float);
    __hip_bfloat16* ebuf = (__hip_bfloat16*)ws2;
    const int nb_e16 = (E + TILE - 1) / TILE;

    node_enc_kernel<<<nb_n16, 256, 0, stream>>>(
        ati, aci, rci, rsi, emb_at, emb_ac, emb_rc, emb_ri,
        nenc_w1, nenc_b1, nenc_w2, nenc_b2, hbuf2, (unsigned short*)nullptr, N);

    edge_enc_kernel<__hip_bfloat16><<<nb_e16, 256, 0, stream>>>(
        pos, c_in, snd, rcv, bnd, emb_bond,
        eenc_w1, eenc_b1, eenc_w2, eenc_b2, ebuf, cutbuf2, E);

    for (int s = 0; s < 4; ++s) {
      zero_kernel<<<(n4 + 255) / 256, 256, 0, stream>>>((float4*)aggbuf2, n4);
      msg_kernel<__hip_bfloat16><<<nb_e16, 256, 0, stream>>>(
          hbuf2, ebuf, aggbuf2, cutbuf2, snd, rcv,
          msg_w1 + (size_t)s * 384 * 256, msg_b1 + (size_t)s * 256,
          msg_w2 + (size_t)s * 256 * 128, msg_b2 + (size_t)s * 128,
          gate_w + (size_t)s * 128, gate_b + s, E);
      upd_kernel<<<nb_n16, 256, 0, stream>>>(
          hbuf2, aggbuf2,
          upd_w1 + (size_t)s * 256 * 256, upd_b1 + (size_t)s * 256,
          upd_w2 + (size_t)s * 256 * 128, upd_b2 + (size_t)s * 128, N);
    }

    head_kernel<<<nb_n16, 256, 0, stream>>>(
        hbuf2, head_w1, head_b1, head_w2, head_b2, (float*)d_out, N);
  }
}